// Round 3
// baseline (299.568 us; speedup 1.0000x reference)
//
#include <hip/hip_runtime.h>

#define NND   8192
#define DDIM  256
#define NGRP  32
#define ZEROF 1e-8f
#define LSTR  40   // K-loop LDS row stride in u16 (80 B: 16B-aligned, 2-way banks free)
#define TSTR  72   // epilogue transpose tile stride in u16 (144 B)
// flat LDS layout (u16 units). TT aliases the B-staging buffers (dead after the
// K-loop, separated by __syncthreads). 32 KB/block -> exactly 5 blocks/CU.
#define OFF_AH 0
#define OFF_AL 2560
#define OFF_BH 5120
#define OFF_BL 10240
#define OFF_TT 5120          // aliases BH/BL region: 128*72=9216 u16 <= 10240
#define LDS_U16 16384

typedef unsigned short u16;
typedef __attribute__((ext_vector_type(8))) short short8v;
typedef __attribute__((ext_vector_type(4))) float float4v;

__device__ inline u16 f2bf(float x) {
  unsigned u = __float_as_uint(x);
  u += 0x7fffu + ((u >> 16) & 1u);
  return (u16)(u >> 16);
}
__device__ inline float bf2f(u16 h) { return __uint_as_float((unsigned)h << 16); }
__device__ inline void split2(float x, u16& h, u16& l) {
  h = f2bf(x);
  l = f2bf(x - bf2f(h));
}

__device__ inline float wave_sum(float v) {
#pragma unroll
  for (int off = 32; off > 0; off >>= 1) v += __shfl_down(v, off, 64);
  return v;
}

// ================= unified split-bf16 MFMA GEMM body =================
// C-tile 64 x (HALF?64:128), 4 waves, 16x16x32 bf16 MFMA, split-bf16x3.
// MODE 0: XWT[c][node] = (H @ Wcat)^T      a=H(node), b=Wt(c)          [full]
// MODE 1: Hout = relu(b3 + M @ XWcat)      a=XWT(d), b=Mb h/l, K=768   [full]
// MODE 2: A = (x.xT)*di*dj/(ni*nj+eps)     a=b=x                       [half]
// MODE 3: A = 0.5A + 0.5 sigmoid(t.HT)     a=tmp, b=H                  [half]
// MODE 4: tmp[node][d] = H @ T             a=Tt(d), b=H(node)          [half]
#define LOAD_REGS(tt, kk)                                                                   \
  {                                                                                         \
    int m_ = tid >> 2, kq_ = (tid & 3) * 8;                                                 \
    size_t aoff_;                                                                           \
    if (MODE == 1)                                                                          \
      aoff_ = (size_t)((tt) * 256 + bym * 64 + m_) * 8192 + (size_t)(g * 256 + (kk) + kq_); \
    else if (MODE == 2 || MODE == 3)                                                        \
      aoff_ = (size_t)(g * 256 + bym * 64 + m_) * 256 + (kk) + kq_;                         \
    else                                                                                    \
      aoff_ = (size_t)(bym * 64 + m_) * 256 + (kk) + kq_;                                   \
    rAh = *(const short8v*)&Ah_g[aoff_];                                                    \
    rAl = *(const short8v*)&Al_g[aoff_];                                                    \
    size_t bbase_ = (MODE == 1) ? ((size_t)(g * 3 + (tt)) << 16)                            \
                  : ((MODE == 2 || MODE == 3) ? ((size_t)g << 16) : (size_t)0);             \
    if (HALF) {                                                                             \
      int n_ = tid & 63, kq2_ = (tid >> 6) * 8;                                             \
      size_t boff_ = bbase_ + (size_t)(col0 + n_) * 256 + (kk) + kq2_;                      \
      rBh0 = *(const short8v*)&Bh_g[boff_];                                                 \
      rBl0 = *(const short8v*)&Bl_g[boff_];                                                 \
    } else {                                                                                \
      int n_ = tid & 127, kq2_ = (tid >> 7) * 16;                                           \
      size_t boff_ = bbase_ + (size_t)(col0 + n_) * 256 + (kk) + kq2_;                      \
      rBh0 = *(const short8v*)&Bh_g[boff_]; rBh1 = *(const short8v*)&Bh_g[boff_ + 8];       \
      rBl0 = *(const short8v*)&Bl_g[boff_]; rBl1 = *(const short8v*)&Bl_g[boff_ + 8];       \
    }                                                                                       \
  }

template<int MODE, bool HALF>
__device__ __forceinline__ void mfma_body(
    u16* lds,
    const u16* __restrict__ Ah_g, const u16* __restrict__ Al_g,
    const u16* __restrict__ Bh_g, const u16* __restrict__ Bl_g,
    float* __restrict__ Cf, u16* __restrict__ Ch, u16* __restrict__ Cl,
    const float* __restrict__ nrm, const float* __restrict__ dinv,
    const float* __restrict__ bias,
    int bxm, int bym, int g) {
  u16* Ahs = lds + OFF_AH;
  u16* Als = lds + OFF_AL;
  u16* Bhs = lds + OFF_BH;
  u16* Bls = lds + OFF_BL;
  u16* Tt  = lds + OFF_TT;    // aliases Bhs/Bls — only used after K-loop + sync
  const int NJ = HALF ? 2 : 4;
  const int tid = threadIdx.x;
  const int col0 = bxm * (HALF ? 64 : 128);
  const int w = tid >> 6, lane = tid & 63;
  const int lm = lane & 15, lq = lane >> 4;
  const int wr = (w >> 1) * 32, wc = (w & 1) * (HALF ? 32 : 64);

  float4v acc[2][4];
#pragma unroll
  for (int i = 0; i < 2; ++i)
#pragma unroll
    for (int j = 0; j < NJ; ++j) acc[i][j] = (float4v)0.f;

  short8v rAh, rAl, rBh0, rBh1, rBl0, rBl1;
  const int TOTAL = (MODE == 1) ? 24 : 8;

  LOAD_REGS(0, 0);
  for (int step = 0; step < TOTAL; ++step) {
    if (step) __syncthreads();
    {
      int m = tid >> 2, kq = (tid & 3) * 8;
      *(short8v*)&Ahs[m * LSTR + kq] = rAh;
      *(short8v*)&Als[m * LSTR + kq] = rAl;
    }
    if (HALF) {
      int n = tid & 63, kq2 = (tid >> 6) * 8;
      *(short8v*)&Bhs[n * LSTR + kq2] = rBh0;
      *(short8v*)&Bls[n * LSTR + kq2] = rBl0;
    } else {
      int n = tid & 127, kq2 = (tid >> 7) * 16;
      *(short8v*)&Bhs[n * LSTR + kq2] = rBh0; *(short8v*)&Bhs[n * LSTR + kq2 + 8] = rBh1;
      *(short8v*)&Bls[n * LSTR + kq2] = rBl0; *(short8v*)&Bls[n * LSTR + kq2 + 8] = rBl1;
    }
    __syncthreads();
    int nxt = step + 1;
    if (nxt < TOTAL) {
      int tt = nxt >> 3, kk = (nxt & 7) * 32;
      LOAD_REGS(tt, kk);
    }
    short8v ah[2], al[2], bh[4], bl[4];
#pragma unroll
    for (int i = 0; i < 2; ++i) {
      int r = wr + i * 16 + lm;
      ah[i] = *(const short8v*)&Ahs[r * LSTR + lq * 8];
      al[i] = *(const short8v*)&Als[r * LSTR + lq * 8];
    }
#pragma unroll
    for (int j = 0; j < NJ; ++j) {
      int r = wc + j * 16 + lm;
      bh[j] = *(const short8v*)&Bhs[r * LSTR + lq * 8];
      bl[j] = *(const short8v*)&Bls[r * LSTR + lq * 8];
    }
#pragma unroll
    for (int i = 0; i < 2; ++i)
#pragma unroll
      for (int j = 0; j < NJ; ++j) {
        acc[i][j] = __builtin_amdgcn_mfma_f32_16x16x32_bf16(ah[i], bh[j], acc[i][j], 0, 0, 0);
        acc[i][j] = __builtin_amdgcn_mfma_f32_16x16x32_bf16(ah[i], bl[j], acc[i][j], 0, 0, 0);
        acc[i][j] = __builtin_amdgcn_mfma_f32_16x16x32_bf16(al[i], bh[j], acc[i][j], 0, 0, 0);
      }
  }

  // ---- epilogues (frag: col=lm, row=lq*4+r) ----
  if (MODE == 2 || MODE == 3) {
#pragma unroll
    for (int i = 0; i < 2; ++i) {
#pragma unroll
      for (int r = 0; r < 4; ++r) {
        int grow = g * 256 + bym * 64 + wr + i * 16 + lq * 4 + r;
        float di = 0.f, ni = 0.f;
        if (MODE == 2) { di = dinv[grow]; ni = nrm[grow]; }
#pragma unroll
        for (int j = 0; j < NJ; ++j) {
          int gcol = col0 + wc + j * 16 + lm;
          size_t ci = (size_t)grow * 256 + gcol;
          float v = acc[i][j][r];
          if (MODE == 2) {
            int gj = g * 256 + gcol;
            Cf[ci] = v * di * dinv[gj] / (ni * nrm[gj] + ZEROF);
          } else {
            Cf[ci] = 0.5f * Cf[ci] + 0.5f * (1.f / (1.f + expf(-v)));
          }
        }
      }
    }
  } else {
    float bsum[8];
    if (MODE == 1) {
#pragma unroll
      for (int i = 0; i < 2; ++i)
#pragma unroll
        for (int r = 0; r < 4; ++r) {
          int d = bym * 64 + wr + i * 16 + lq * 4 + r;
          bsum[i * 4 + r] = bias[d] + bias[256 + d] + bias[512 + d];
        }
    }
    u16 hv[32], lv[32];
#pragma unroll
    for (int i = 0; i < 2; ++i)
#pragma unroll
      for (int j = 0; j < NJ; ++j)
#pragma unroll
        for (int r = 0; r < 4; ++r) {
          float v = acc[i][j][r];
          if (MODE == 1) v = fmaxf(v + bsum[i * 4 + r], 0.f);
          split2(v, hv[(i * 4 + r) * NJ + j], lv[(i * 4 + r) * NJ + j]);
        }
    int ebase1 = (MODE == 1) ? (g * 256 + col0) : col0;
    int ebase2 = bym * 64;
    size_t estride = (MODE == 0) ? 8192 : 256;
#pragma unroll
    for (int ph = 0; ph < 2; ++ph) {
      __syncthreads();
      const u16* sv = ph ? lv : hv;
#pragma unroll
      for (int i = 0; i < 2; ++i)
#pragma unroll
        for (int j = 0; j < NJ; ++j)
#pragma unroll
          for (int r = 0; r < 4; ++r)
            Tt[(wc + j * 16 + lm) * TSTR + wr + i * 16 + lq * 4 + r] = sv[(i * 4 + r) * NJ + j];
      __syncthreads();
      u16* dst = ph ? Cl : Ch;
      int cc0 = tid >> 3, mm0 = (tid & 7) * 8;
#pragma unroll
      for (int it = 0; it < (HALF ? 2 : 4); ++it) {
        int cc = it * 32 + cc0;
        short8v v = *(const short8v*)&Tt[cc * TSTR + mm0];
        *(short8v*)&dst[(size_t)(ebase1 + cc) * estride + ebase2 + mm0] = v;
      }
    }
  }
}

// ===== prep: mask cvt | edge bucketing (atomic-free) | transpose/split W | norms+x-split =====
__global__ void k_prep(const int* __restrict__ e0, const int* __restrict__ e1,
                       const int* __restrict__ e2, const unsigned char* __restrict__ m0,
                       const unsigned char* __restrict__ m1,
                       const float* __restrict__ W, const float* __restrict__ T,
                       const float* __restrict__ x,
                       const float* __restrict__ ew0, const float* __restrict__ ew1,
                       const float* __restrict__ ew2,
                       float* __restrict__ emf, float* __restrict__ pmf,
                       u16* __restrict__ Wth, u16* __restrict__ Wtl,
                       u16* __restrict__ sct, uint2* __restrict__ recs,
                       float* __restrict__ nrm, float* __restrict__ Spart,
                       u16* __restrict__ Hh, u16* __restrict__ Hl,
                       int E_, int nCvt, int nBkt) {
  __shared__ float tile[32][33];
  __shared__ float inv[64];
  __shared__ int nz[1];
  __shared__ unsigned int hcnt[768];
  __shared__ unsigned int hoff[768];
  __shared__ unsigned int ppart[256];
  __shared__ uint2 stage[768];
  const int b = blockIdx.x, tid = threadIdx.x;
  if (b < nCvt) {
    // ---- mask dtype detect + convert (2*NND values) ----
    if (tid == 0) nz[0] = 0;
    __syncthreads();
    int i4 = tid * 4;
    int c = (m0[i4 + 1] != 0) + (m0[i4 + 2] != 0) + (m0[i4 + 3] != 0);
    if (c) atomicAdd(&nz[0], c);
    __syncthreads();
    int fM = (nz[0] == 0);
    int i = b * 256 + tid;
    if (i < NND) {
      unsigned char v = fM ? m0[4 * i] : m0[i];
      emf[i] = 1.f - (float)(v != 0);
    } else {
      int j = i - NND;
      unsigned char v = fM ? m1[4 * j] : m1[j];
      pmf[j] = 1.f - (float)(v != 0);
    }
  } else if (b < nCvt + nBkt) {
    // ---- atomic-free edge bucketing: block-private segments, LDS hist+scan ----
    if (tid == 0) nz[0] = 0;
    hcnt[tid] = 0; hcnt[tid + 256] = 0; hcnt[tid + 512] = 0;
    __syncthreads();
    if (e0[2 * tid + 1] != 0) atomicAdd(&nz[0], 1);
    __syncthreads();
    int fE = (nz[0] == 0);   // int64-format edges
    int e = (b - nCvt) * 256 + tid;
    bool valid = (e < E_);
    int mybid[3]; unsigned int myrec[3]; float myw[3];
    if (valid) {
#pragma unroll
      for (int t = 0; t < 3; ++t) {
        const int* ei = (t == 0) ? e0 : ((t == 1) ? e1 : e2);
        int src = fE ? ei[2 * e] : ei[e];
        int dst = fE ? ei[2 * (E_ + e)] : ei[E_ + e];
        int g = src >> 8, s = src & 255, d = dst & 255;
        mybid[t] = ((g * 3 + t) << 3) | (d >> 5);
        myrec[t] = (unsigned)(((d & 31) << 8) | s);
        myw[t] = (t == 0 ? ew0 : (t == 1 ? ew1 : ew2))[e];
        atomicAdd(&hcnt[mybid[t]], 1u);
      }
    }
    __syncthreads();
    unsigned c0 = hcnt[3 * tid], c1 = hcnt[3 * tid + 1], c2 = hcnt[3 * tid + 2];
    unsigned tsum = c0 + c1 + c2;
    ppart[tid] = tsum;
    __syncthreads();
    for (int off = 1; off < 256; off <<= 1) {
      unsigned v = (tid >= off) ? ppart[tid - off] : 0u;
      __syncthreads();
      ppart[tid] += v;
      __syncthreads();
    }
    unsigned base = ppart[tid] - tsum;   // exclusive prefix
    hoff[3 * tid] = base;
    hoff[3 * tid + 1] = base + c0;
    hoff[3 * tid + 2] = base + c0 + c1;
    __syncthreads();
#pragma unroll
    for (int k = 0; k < 3; ++k) {
      int bin = tid + k * 256;
      unsigned cc = hcnt[bin]; if (cc > 31u) cc = 31u;
      sct[(size_t)(b - nCvt) * 768 + bin] = (u16)(hoff[bin] | (cc << 11));
    }
    __syncthreads();
    if (valid) {
#pragma unroll
      for (int t = 0; t < 3; ++t) {
        unsigned slot = atomicAdd(&hoff[mybid[t]], 1u);
        stage[slot] = make_uint2(myrec[t], __float_as_uint(myw[t]));
      }
    }
    __syncthreads();
    uint2* dstp = &recs[(size_t)(b - nCvt) * 768];
    dstp[tid] = stage[tid];
    dstp[tid + 256] = stage[tid + 256];
    dstp[tid + 512] = stage[tid + 512];
  } else if (b < nCvt + nBkt + 512) {
    int bb = b - nCvt - nBkt;
    int mat = bb >> 6, rem = bb & 63;
    int k0 = (rem >> 3) * 32, n0 = (rem & 7) * 32;
    const float* src = (mat < 6) ? (W + (size_t)mat * 65536) : (T + (size_t)(mat - 6) * 65536);
    int r = tid >> 3, c4 = (tid & 7) * 4;
    const float4 v = *(const float4*)&src[(size_t)(k0 + r) * 256 + n0 + c4];
    tile[r][c4 + 0] = v.x; tile[r][c4 + 1] = v.y; tile[r][c4 + 2] = v.z; tile[r][c4 + 3] = v.w;
    __syncthreads();
    float o[4] = {tile[c4 + 0][r], tile[c4 + 1][r], tile[c4 + 2][r], tile[c4 + 3][r]};
    u16 hh[4], ll[4];
#pragma unroll
    for (int q = 0; q < 4; ++q) split2(o[q], hh[q], ll[q]);
    size_t off = (size_t)mat * 65536 + (size_t)(n0 + r) * 256 + k0 + c4;
    *(ushort4*)&Wth[off] = *(ushort4*)hh;
    *(ushort4*)&Wtl[off] = *(ushort4*)ll;
  } else {
    int bn = b - nCvt - nBkt - 512;    // 0..127
    int n0 = bn * 64;
    int w = tid >> 6, lane = tid & 63;
    for (int it = 0; it < 16; ++it) {
      int nl = it * 4 + w;
      int node = n0 + nl;
      const float4 v = *(const float4*)&x[(size_t)node * 256 + lane * 4];
      u16 hh[4], ll[4];
      split2(v.x, hh[0], ll[0]); split2(v.y, hh[1], ll[1]);
      split2(v.z, hh[2], ll[2]); split2(v.w, hh[3], ll[3]);
      *(ushort4*)&Hh[(size_t)node * 256 + lane * 4] = *(ushort4*)hh;
      *(ushort4*)&Hl[(size_t)node * 256 + lane * 4] = *(ushort4*)ll;
      float s = wave_sum(v.x * v.x + v.y * v.y + v.z * v.z + v.w * v.w);
      if (lane == 0) { float nr = sqrtf(s); nrm[node] = nr; inv[nl] = 1.f / nr; }
    }
    __syncthreads();
    float s = 0.f;
    for (int i = 0; i < 64; ++i) s += x[(size_t)(n0 + i) * 256 + tid] * inv[i];
    Spart[bn * 256 + tid] = s;
  }
}

// ============ k_gemmA: mode0 GEMM only (768 blocks) — split out for attribution ============
__global__ __launch_bounds__(256, 2) void k_gemmA(
    const u16* __restrict__ Hinh, const u16* __restrict__ Hinl,
    const u16* __restrict__ Wth, const u16* __restrict__ Wtl, int l,
    u16* __restrict__ XWTh, u16* __restrict__ XWTl) {
  __shared__ u16 lds[LDS_U16];
  const int b = blockIdx.x;
  // XCD-aware: same H row-block -> same b mod 8 -> same XCD L2
  mfma_body<0, false>(lds, Hinh, Hinl, Wth + (size_t)l * 768 * 256,
                      Wtl + (size_t)l * 768 * 256,
                      nullptr, XWTh, XWTl, nullptr, nullptr, nullptr,
                      b >> 7, b & 127, 0);
}

// ==== k_mbuild: dense M tiles from buckets, emitted as bf16 h/l | (l0) dinv blocks ====
// Zero a 32x256 fp32 LDS tile; gather this bucket's records from all source-block
// segments; LDS-atomic accumulate; split to bf16 h/l ONCE and stream out coalesced.
// Pre-splitting here removes 24 steps x 16 split2 from every mode-1 GEMM block.
__global__ __launch_bounds__(256, 2) void k_mbuild(
    const u16* __restrict__ sct, const uint2* __restrict__ recs, int nBkt,
    const float* __restrict__ Abuf, u16* __restrict__ Mbh, u16* __restrict__ Mbl, int l,
    const float* __restrict__ x, const float* __restrict__ Spart,
    const float* __restrict__ nrm, float* __restrict__ dinv) {
  __shared__ float tile[8192];   // 32 KB
  const int b = blockIdx.x, tid = threadIdx.x;
  if (b < 768) {
    int bid = b;                 // bucket id = ((g*3+t)<<3)|chunk
    int gt = bid >> 3, chunk = bid & 7;
    int g = gt / 3;
    float4 z = make_float4(0.f, 0.f, 0.f, 0.f);
#pragma unroll
    for (int k = 0; k < 8; ++k) ((float4*)tile)[k * 256 + tid] = z;
    __syncthreads();
    for (int bb = tid; bb < nBkt; bb += 256) {
      unsigned sc = sct[(size_t)bb * 768 + bid];
      unsigned start = sc & 2047u, cnt = sc >> 11;
      const uint2* rp = &recs[(size_t)bb * 768 + start];
      for (unsigned k = 0; k < cnt; ++k) {
        uint2 r = rp[k];
        int s = r.x & 255, d5 = (r.x >> 8) & 31;
        float w = l ? Abuf[(size_t)(g * 256 + s) * 256 + chunk * 32 + d5]
                    : __uint_as_float(r.y);
        atomicAdd(&tile[d5 * 256 + s], w);
      }
    }
    __syncthreads();
    size_t base4 = ((size_t)gt << 14) + ((size_t)chunk << 11);  // ushort4 units
#pragma unroll
    for (int k = 0; k < 8; ++k) {
      float4 f = ((float4*)tile)[k * 256 + tid];
      ushort4 h, lo;
      split2(f.x, h.x, lo.x); split2(f.y, h.y, lo.y);
      split2(f.z, h.z, lo.z); split2(f.w, h.w, lo.w);
      ((ushort4*)Mbh)[base4 + k * 256 + tid] = h;
      ((ushort4*)Mbl)[base4 + k * 256 + tid] = lo;
    }
  } else {
    // dinv blocks (only launched for l==0; grid 896)
    float* Sl = tile;
    float s = 0.f;
    for (int bb = 0; bb < 128; ++bb) s += Spart[bb * 256 + tid];
    Sl[tid] = s;
    __syncthreads();
    int base = (b - 768) * 64;
    int w = tid >> 6, lane = tid & 63;
    const float4 sv = *(const float4*)&Sl[lane * 4];
    for (int it = 0; it < 16; ++it) {
      int node = base + it * 4 + w;
      const float4 v = *(const float4*)&x[(size_t)node * 256 + lane * 4];
      float s2 = wave_sum(v.x * sv.x + v.y * sv.y + v.z * sv.z + v.w * sv.w);
      if (lane == 0) {
        float rowsum = s2 / nrm[node];
        dinv[node] = rsqrtf(fabsf(rowsum) + ZEROF);
      }
    }
  }
}

// ==== stage B: mode1 (FULL 64x128, first 256 blocks) | (l0 only) mode2 (half, 512) ====
__global__ __launch_bounds__(256, 2) void k_stageB(
    const u16* __restrict__ XWTh, const u16* __restrict__ XWTl,
    const u16* __restrict__ Mbh, const u16* __restrict__ Mbl,
    u16* __restrict__ Houth, u16* __restrict__ Houtl, const float* __restrict__ bias,
    const u16* __restrict__ xh, const u16* __restrict__ xl, float* __restrict__ Abuf,
    const float* __restrict__ nrm, const float* __restrict__ dinv) {
  __shared__ u16 lds[LDS_U16];
  const int b = blockIdx.x;
  if (b < 256) {
    int g = b & 31, r = b >> 5;        // r: 0..7 -> bym 0..3, bxm 0..1
    mfma_body<1, false>(lds, XWTh, XWTl, Mbh, Mbl,
                        nullptr, Houth, Houtl, nullptr, nullptr, bias,
                        r & 1, r >> 1, g);
  } else {
    int bb = b - 256;
    int g = bb & 31, r = bb >> 5;      // r: 0..15 -> bym 0..3, bxm 0..3
    mfma_body<2, true>(lds, xh, xl, xh, xl, Abuf, nullptr, nullptr,
                       nrm, dinv, nullptr, r >> 2, r & 3, g);
  }
}

// ============ stage C: mode4 (half, 512): tmp = H @ T ============
__global__ __launch_bounds__(256, 2) void k_stageC(
    const u16* __restrict__ Wth, const u16* __restrict__ Wtl, int l,
    const u16* __restrict__ Hh, const u16* __restrict__ Hl,
    u16* __restrict__ tmph, u16* __restrict__ tmpl) {
  __shared__ u16 lds[LDS_U16];
  const int b = blockIdx.x;
  mfma_body<4, true>(lds, Wth + (size_t)(6 + l) * 65536, Wtl + (size_t)(6 + l) * 65536,
                     Hh, Hl, nullptr, tmph, tmpl, nullptr, nullptr, nullptr,
                     b & 127, b >> 7, 0);
}

// ============ stage D: mode3 (half, 512): A update ============
__global__ __launch_bounds__(256, 2) void k_stageD(
    const u16* __restrict__ tmph, const u16* __restrict__ tmpl,
    const u16* __restrict__ Hh, const u16* __restrict__ Hl,
    float* __restrict__ Abuf) {
  __shared__ u16 lds[LDS_U16];
  const int b = blockIdx.x;
  int g = b & 31, r = b >> 5;
  mfma_body<3, true>(lds, tmph, tmpl, Hh, Hl, Abuf, nullptr, nullptr,
                     nullptr, nullptr, nullptr, r >> 2, r & 3, g);
}

// ============ fused maps ============
__global__ void k_maps(const float* __restrict__ Abuf, const float* __restrict__ emf,
                       const float* __restrict__ pmf, float* __restrict__ out) {
  __shared__ float sme[256], smp[256], red[256];
  const int g = blockIdx.x, tid = threadIdx.x, w = tid >> 6, lane = tid & 63;
  const int j0 = g * 256 + lane * 4;
  const float4 pmv = *(const float4*)&pmf[j0];
  const float4 emv = *(const float4*)&emf[j0];
  for (int it = 0; it < 64; ++it) {
    int nl = it * 4 + w;
    const float4 a = *(const float4*)&Abuf[((size_t)g * 256 + nl) * 256 + lane * 4];
    float me = a.x * pmv.x + a.y * pmv.y + a.z * pmv.z + a.w * pmv.w;
    float mp = a.x * emv.x + a.y * emv.y + a.z * emv.z + a.w * emv.w;
#pragma unroll
    for (int off = 32; off > 0; off >>= 1) {
      me += __shfl_down(me, off, 64);
      mp += __shfl_down(mp, off, 64);
    }
    if (lane == 0) { sme[nl] = me; smp[nl] = mp; }
  }
  __syncthreads();
  for (int which = 0; which < 2; ++which) {
    float v = which ? smp[tid] : sme[tid];
    red[tid] = v; __syncthreads();
    for (int s = 128; s > 0; s >>= 1) { if (tid < s) red[tid] = fminf(red[tid], red[tid + s]); __syncthreads(); }
    float mn = red[0]; __syncthreads();
    red[tid] = v; __syncthreads();
    for (int s = 128; s > 0; s >>= 1) { if (tid < s) red[tid] = fmaxf(red[tid], red[tid + s]); __syncthreads(); }
    float mx = red[0]; __syncthreads();
    float m = (v - mn) / (mx - mn + ZEROF);
    red[tid] = m; __syncthreads();
    for (int s = 128; s > 0; s >>= 1) { if (tid < s) red[tid] += red[tid + s]; __syncthreads(); }
    float sum = red[0]; __syncthreads();
    out[which * NND + g * 256 + tid] = m / (sum + ZEROF);
  }
}

// ================= launch =================
extern "C" void kernel_launch(void* const* d_in, const int* in_sizes, int n_in,
                              void* d_out, int out_size, void* d_ws, size_t ws_size,
                              hipStream_t stream) {
  const float* x = (const float*)d_in[0];
  const unsigned char* em_raw = (const unsigned char*)d_in[7];
  const unsigned char* pm_raw = (const unsigned char*)d_in[8];
  const float* W  = (const float*)d_in[9];
  const float* bg = (const float*)d_in[10];
  const float* T  = (const float*)d_in[11];
  float* out = (float*)d_out;
  const int E_ = in_sizes[2];

  const int nCvt = (2 * NND) / 256;          // 64
  const int nBkt = (E_ + 255) / 256;         // 512 for E=131072

  float* ws = (float*)d_ws;
  size_t o = 0;
  float* Abuf = ws + o; o += (size_t)NND * 256;
  u16* Mbh_l0 = (u16*)(ws + o); o += (size_t)NGRP * 3 * 65536 / 2;
  u16* Mbl_l0 = (u16*)(ws + o); o += (size_t)NGRP * 3 * 65536 / 2;
  u16* Mbh_l1 = (u16*)(ws + o); o += (size_t)NGRP * 3 * 65536 / 2;
  u16* Mbl_l1 = (u16*)(ws + o); o += (size_t)NGRP * 3 * 65536 / 2;
  u16* Hh   = (u16*)(ws + o); o += (size_t)NND * 256 / 2;
  u16* Hl   = (u16*)(ws + o); o += (size_t)NND * 256 / 2;
  u16* H2h  = (u16*)(ws + o); o += (size_t)NND * 256 / 2;
  u16* H2l  = (u16*)(ws + o); o += (size_t)NND * 256 / 2;
  u16* tmph = (u16*)(ws + o); o += (size_t)NND * 256 / 2;
  u16* tmpl = (u16*)(ws + o); o += (size_t)NND * 256 / 2;
  u16* XWTh = (u16*)(ws + o); o += (size_t)768 * NND / 2;
  u16* XWTl = (u16*)(ws + o); o += (size_t)768 * NND / 2;
  u16* Wth  = (u16*)(ws + o); o += (size_t)8 * 65536 / 2;
  u16* Wtl  = (u16*)(ws + o); o += (size_t)8 * 65536 / 2;
  float* nrm   = ws + o; o += NND;
  float* dinv  = ws + o; o += NND;
  float* Spart = ws + o; o += 128 * 256;
  float* emf   = ws + o; o += NND;
  float* pmf   = ws + o; o += NND;
  u16* sct     = (u16*)(ws + o); o += (size_t)nBkt * 768 / 2;
  uint2* recs  = (uint2*)(ws + o); o += (size_t)nBkt * 768 * 2;

  const float* ew0 = (const float*)d_in[2];
  const float* ew1 = (const float*)d_in[4];
  const float* ew2 = (const float*)d_in[6];

  k_prep<<<nCvt + nBkt + 512 + 128, 256, 0, stream>>>(
      (const int*)d_in[1], (const int*)d_in[3], (const int*)d_in[5], em_raw, pm_raw,
      W, T, x, ew0, ew1, ew2, emf, pmf, Wth, Wtl, sct, recs,
      nrm, Spart, Hh, Hl, E_, nCvt, nBkt);

  // ---- layer 0 ----
  k_gemmA<<<768, 256, 0, stream>>>(Hh, Hl, Wth, Wtl, 0, XWTh, XWTl);
  k_mbuild<<<896, 256, 0, stream>>>(sct, recs, nBkt, Abuf, Mbh_l0, Mbl_l0, 0,
                                    x, Spart, nrm, dinv);
  k_stageB<<<768, 256, 0, stream>>>(XWTh, XWTl, Mbh_l0, Mbl_l0, H2h, H2l, bg,
                                    Hh, Hl, Abuf, nrm, dinv);
  k_stageC<<<512, 256, 0, stream>>>(Wth, Wtl, 0, H2h, H2l, tmph, tmpl);
  k_stageD<<<512, 256, 0, stream>>>(tmph, tmpl, H2h, H2l, Abuf);

  // ---- layer 1 ----
  k_gemmA<<<768, 256, 0, stream>>>(H2h, H2l, Wth, Wtl, 1, XWTh, XWTl);
  k_mbuild<<<768, 256, 0, stream>>>(sct, recs, nBkt, Abuf, Mbh_l1, Mbl_l1, 1,
                                    x, Spart, nrm, dinv);
  k_stageB<<<256, 256, 0, stream>>>(XWTh, XWTl, Mbh_l1, Mbl_l1, Hh, Hl, bg + 768,
                                    nullptr, nullptr, nullptr, nullptr, nullptr);
  k_stageC<<<512, 256, 0, stream>>>(Wth, Wtl, 1, Hh, Hl, tmph, tmpl);
  k_stageD<<<512, 256, 0, stream>>>(tmph, tmpl, Hh, Hl, Abuf);

  k_maps<<<NGRP, 256, 0, stream>>>(Abuf, emf, pmf, out);
}

// Round 4
// 296.468 us; speedup vs baseline: 1.0105x; 1.0105x over previous
//
#include <hip/hip_runtime.h>

#define NND   8192
#define DDIM  256
#define NGRP  32
#define ZEROF 1e-8f
#define LSTR  40   // K-loop LDS row stride in u16 (80 B: 16B-aligned, 2-way banks free)
#define TSTR  72   // epilogue transpose tile stride in u16 (144 B)
// flat LDS layout (u16 units). TT aliases the B-staging buffers (dead after the
// K-loop, separated by __syncthreads). 32 KB/block.
#define OFF_AH 0
#define OFF_AL 2560
#define OFF_BH 5120
#define OFF_BL 10240
#define OFF_TT 5120          // aliases BH/BL region: 128*72=9216 u16 <= 10240
#define LDS_U16 16384

typedef unsigned short u16;
typedef __attribute__((ext_vector_type(8))) short short8v;
typedef __attribute__((ext_vector_type(4))) float float4v;

__device__ inline u16 f2bf(float x) {
  unsigned u = __float_as_uint(x);
  u += 0x7fffu + ((u >> 16) & 1u);
  return (u16)(u >> 16);
}
__device__ inline float bf2f(u16 h) { return __uint_as_float((unsigned)h << 16); }
__device__ inline void split2(float x, u16& h, u16& l) {
  h = f2bf(x);
  l = f2bf(x - bf2f(h));
}

__device__ inline float wave_sum(float v) {
#pragma unroll
  for (int off = 32; off > 0; off >>= 1) v += __shfl_down(v, off, 64);
  return v;
}

// ================= unified split-bf16 MFMA GEMM body =================
// C-tile 64 x (HALF?64:128), 4 waves, 16x16x32 bf16 MFMA, split-bf16x3.
// MODE 0: XWT[c][node] = (H @ Wcat)^T      a=H(node), b=Wt(c)          [full]
// MODE 1: Hout = relu(b3 + M @ XWcat)      a=XWT(d), b=Mb h/l, K=768   [full]
// MODE 2: A = (x.xT)*di*dj/(ni*nj+eps)     a=b=x                       [half]
// MODE 3: A = 0.5A + 0.5 sigmoid(t.HT)     a=tmp, b=H                  [half]
// MODE 4: tmp[node][d] = H @ T             a=Tt(d), b=H(node)          [half]
#define LOAD_REGS(tt, kk)                                                                   \
  {                                                                                         \
    int m_ = tid >> 2, kq_ = (tid & 3) * 8;                                                 \
    size_t aoff_;                                                                           \
    if (MODE == 1)                                                                          \
      aoff_ = (size_t)((tt) * 256 + bym * 64 + m_) * 8192 + (size_t)(g * 256 + (kk) + kq_); \
    else if (MODE == 2 || MODE == 3)                                                        \
      aoff_ = (size_t)(g * 256 + bym * 64 + m_) * 256 + (kk) + kq_;                         \
    else                                                                                    \
      aoff_ = (size_t)(bym * 64 + m_) * 256 + (kk) + kq_;                                   \
    rAh = *(const short8v*)&Ah_g[aoff_];                                                    \
    rAl = *(const short8v*)&Al_g[aoff_];                                                    \
    size_t bbase_ = (MODE == 1) ? ((size_t)(g * 3 + (tt)) << 16)                            \
                  : ((MODE == 2 || MODE == 3) ? ((size_t)g << 16) : (size_t)0);             \
    if (HALF) {                                                                             \
      int n_ = tid & 63, kq2_ = (tid >> 6) * 8;                                             \
      size_t boff_ = bbase_ + (size_t)(col0 + n_) * 256 + (kk) + kq2_;                      \
      rBh0 = *(const short8v*)&Bh_g[boff_];                                                 \
      rBl0 = *(const short8v*)&Bl_g[boff_];                                                 \
    } else {                                                                                \
      int n_ = tid & 127, kq2_ = (tid >> 7) * 16;                                           \
      size_t boff_ = bbase_ + (size_t)(col0 + n_) * 256 + (kk) + kq2_;                      \
      rBh0 = *(const short8v*)&Bh_g[boff_]; rBh1 = *(const short8v*)&Bh_g[boff_ + 8];       \
      rBl0 = *(const short8v*)&Bl_g[boff_]; rBl1 = *(const short8v*)&Bl_g[boff_ + 8];       \
    }                                                                                       \
  }

template<int MODE, bool HALF>
__device__ __forceinline__ void mfma_body(
    u16* lds,
    const u16* __restrict__ Ah_g, const u16* __restrict__ Al_g,
    const u16* __restrict__ Bh_g, const u16* __restrict__ Bl_g,
    float* __restrict__ Cf, u16* __restrict__ Ch, u16* __restrict__ Cl,
    const float* __restrict__ nrm, const float* __restrict__ dinv,
    const float* __restrict__ bias,
    int bxm, int bym, int g) {
  u16* Ahs = lds + OFF_AH;
  u16* Als = lds + OFF_AL;
  u16* Bhs = lds + OFF_BH;
  u16* Bls = lds + OFF_BL;
  u16* Tt  = lds + OFF_TT;    // aliases Bhs/Bls — only used after K-loop + sync
  const int NJ = HALF ? 2 : 4;
  const int tid = threadIdx.x;
  const int col0 = bxm * (HALF ? 64 : 128);
  const int w = tid >> 6, lane = tid & 63;
  const int lm = lane & 15, lq = lane >> 4;
  const int wr = (w >> 1) * 32, wc = (w & 1) * (HALF ? 32 : 64);

  float4v acc[2][4];
#pragma unroll
  for (int i = 0; i < 2; ++i)
#pragma unroll
    for (int j = 0; j < NJ; ++j) acc[i][j] = (float4v)0.f;

  short8v rAh, rAl, rBh0, rBh1, rBl0, rBl1;
  const int TOTAL = (MODE == 1) ? 24 : 8;

  LOAD_REGS(0, 0);
  for (int step = 0; step < TOTAL; ++step) {
    if (step) __syncthreads();
    {
      int m = tid >> 2, kq = (tid & 3) * 8;
      *(short8v*)&Ahs[m * LSTR + kq] = rAh;
      *(short8v*)&Als[m * LSTR + kq] = rAl;
    }
    if (HALF) {
      int n = tid & 63, kq2 = (tid >> 6) * 8;
      *(short8v*)&Bhs[n * LSTR + kq2] = rBh0;
      *(short8v*)&Bls[n * LSTR + kq2] = rBl0;
    } else {
      int n = tid & 127, kq2 = (tid >> 7) * 16;
      *(short8v*)&Bhs[n * LSTR + kq2] = rBh0; *(short8v*)&Bhs[n * LSTR + kq2 + 8] = rBh1;
      *(short8v*)&Bls[n * LSTR + kq2] = rBl0; *(short8v*)&Bls[n * LSTR + kq2 + 8] = rBl1;
    }
    __syncthreads();
    int nxt = step + 1;
    if (nxt < TOTAL) {
      int tt = nxt >> 3, kk = (nxt & 7) * 32;
      LOAD_REGS(tt, kk);
    }
    short8v ah[2], al[2], bh[4], bl[4];
#pragma unroll
    for (int i = 0; i < 2; ++i) {
      int r = wr + i * 16 + lm;
      ah[i] = *(const short8v*)&Ahs[r * LSTR + lq * 8];
      al[i] = *(const short8v*)&Als[r * LSTR + lq * 8];
    }
#pragma unroll
    for (int j = 0; j < NJ; ++j) {
      int r = wc + j * 16 + lm;
      bh[j] = *(const short8v*)&Bhs[r * LSTR + lq * 8];
      bl[j] = *(const short8v*)&Bls[r * LSTR + lq * 8];
    }
#pragma unroll
    for (int i = 0; i < 2; ++i)
#pragma unroll
      for (int j = 0; j < NJ; ++j) {
        acc[i][j] = __builtin_amdgcn_mfma_f32_16x16x32_bf16(ah[i], bh[j], acc[i][j], 0, 0, 0);
        acc[i][j] = __builtin_amdgcn_mfma_f32_16x16x32_bf16(ah[i], bl[j], acc[i][j], 0, 0, 0);
        acc[i][j] = __builtin_amdgcn_mfma_f32_16x16x32_bf16(al[i], bh[j], acc[i][j], 0, 0, 0);
      }
  }

  // ---- epilogues (frag: col=lm, row=lq*4+r) ----
  if (MODE == 2 || MODE == 3) {
#pragma unroll
    for (int i = 0; i < 2; ++i) {
#pragma unroll
      for (int r = 0; r < 4; ++r) {
        int grow = g * 256 + bym * 64 + wr + i * 16 + lq * 4 + r;
        float di = 0.f, ni = 0.f;
        if (MODE == 2) { di = dinv[grow]; ni = nrm[grow]; }
#pragma unroll
        for (int j = 0; j < NJ; ++j) {
          int gcol = col0 + wc + j * 16 + lm;
          size_t ci = (size_t)grow * 256 + gcol;
          float v = acc[i][j][r];
          if (MODE == 2) {
            int gj = g * 256 + gcol;
            Cf[ci] = v * di * dinv[gj] / (ni * nrm[gj] + ZEROF);
          } else {
            Cf[ci] = 0.5f * Cf[ci] + 0.5f * (1.f / (1.f + expf(-v)));
          }
        }
      }
    }
  } else {
    float bsum[8];
    if (MODE == 1) {
#pragma unroll
      for (int i = 0; i < 2; ++i)
#pragma unroll
        for (int r = 0; r < 4; ++r) {
          int d = bym * 64 + wr + i * 16 + lq * 4 + r;
          bsum[i * 4 + r] = bias[d] + bias[256 + d] + bias[512 + d];
        }
    }
    u16 hv[32], lv[32];
#pragma unroll
    for (int i = 0; i < 2; ++i)
#pragma unroll
      for (int j = 0; j < NJ; ++j)
#pragma unroll
        for (int r = 0; r < 4; ++r) {
          float v = acc[i][j][r];
          if (MODE == 1) v = fmaxf(v + bsum[i * 4 + r], 0.f);
          split2(v, hv[(i * 4 + r) * NJ + j], lv[(i * 4 + r) * NJ + j]);
        }
    int ebase1 = (MODE == 1) ? (g * 256 + col0) : col0;
    int ebase2 = bym * 64;
    size_t estride = (MODE == 0) ? 8192 : 256;
#pragma unroll
    for (int ph = 0; ph < 2; ++ph) {
      __syncthreads();
      const u16* sv = ph ? lv : hv;
#pragma unroll
      for (int i = 0; i < 2; ++i)
#pragma unroll
        for (int j = 0; j < NJ; ++j)
#pragma unroll
          for (int r = 0; r < 4; ++r)
            Tt[(wc + j * 16 + lm) * TSTR + wr + i * 16 + lq * 4 + r] = sv[(i * 4 + r) * NJ + j];
      __syncthreads();
      u16* dst = ph ? Cl : Ch;
      int cc0 = tid >> 3, mm0 = (tid & 7) * 8;
#pragma unroll
      for (int it = 0; it < (HALF ? 2 : 4); ++it) {
        int cc = it * 32 + cc0;
        short8v v = *(const short8v*)&Tt[cc * TSTR + mm0];
        *(short8v*)&dst[(size_t)(ebase1 + cc) * estride + ebase2 + mm0] = v;
      }
    }
  }
}

// ---- M-build block body: dense 32x256 fp32 tile from buckets -> bf16 h/l ----
__device__ __forceinline__ void mbuild_body(
    float* tile, int bid, int l,
    const u16* __restrict__ sct, const uint2* __restrict__ recs, int nBkt,
    const float* __restrict__ Abuf, u16* __restrict__ Mbh, u16* __restrict__ Mbl) {
  const int tid = threadIdx.x;
  int gt = bid >> 3, chunk = bid & 7;
  int g = gt / 3;
  float4 z = make_float4(0.f, 0.f, 0.f, 0.f);
#pragma unroll
  for (int k = 0; k < 8; ++k) ((float4*)tile)[k * 256 + tid] = z;
  __syncthreads();
  for (int bb = tid; bb < nBkt; bb += 256) {
    unsigned sc = sct[(size_t)bb * 768 + bid];
    unsigned start = sc & 2047u, cnt = sc >> 11;
    const uint2* rp = &recs[(size_t)bb * 768 + start];
    for (unsigned k = 0; k < cnt; ++k) {
      uint2 r = rp[k];
      int s = r.x & 255, d5 = (r.x >> 8) & 31;
      float w = l ? Abuf[(size_t)(g * 256 + s) * 256 + chunk * 32 + d5]
                  : __uint_as_float(r.y);
      atomicAdd(&tile[d5 * 256 + s], w);
    }
  }
  __syncthreads();
  size_t base4 = ((size_t)gt << 14) + ((size_t)chunk << 11);  // ushort4 units
#pragma unroll
  for (int k = 0; k < 8; ++k) {
    float4 f = ((float4*)tile)[k * 256 + tid];
    ushort4 h, lo;
    split2(f.x, h.x, lo.x); split2(f.y, h.y, lo.y);
    split2(f.z, h.z, lo.z); split2(f.w, h.w, lo.w);
    ((ushort4*)Mbh)[base4 + k * 256 + tid] = h;
    ((ushort4*)Mbl)[base4 + k * 256 + tid] = lo;
  }
}

// ===== prep: mask cvt | edge bucketing (atomic-free) | transpose/split W | norms+x-split =====
__global__ void k_prep(const int* __restrict__ e0, const int* __restrict__ e1,
                       const int* __restrict__ e2, const unsigned char* __restrict__ m0,
                       const unsigned char* __restrict__ m1,
                       const float* __restrict__ W, const float* __restrict__ T,
                       const float* __restrict__ x,
                       const float* __restrict__ ew0, const float* __restrict__ ew1,
                       const float* __restrict__ ew2,
                       float* __restrict__ emf, float* __restrict__ pmf,
                       u16* __restrict__ Wth, u16* __restrict__ Wtl,
                       u16* __restrict__ sct, uint2* __restrict__ recs,
                       float* __restrict__ nrm, float* __restrict__ Spart,
                       u16* __restrict__ Hh, u16* __restrict__ Hl,
                       int E_, int nCvt, int nBkt) {
  __shared__ float tile[32][33];
  __shared__ float inv[64];
  __shared__ int nz[1];
  __shared__ unsigned int hcnt[768];
  __shared__ unsigned int hoff[768];
  __shared__ unsigned int ppart[256];
  __shared__ uint2 stage[768];
  const int b = blockIdx.x, tid = threadIdx.x;
  if (b < nCvt) {
    // ---- mask dtype detect + convert (2*NND values) ----
    if (tid == 0) nz[0] = 0;
    __syncthreads();
    int i4 = tid * 4;
    int c = (m0[i4 + 1] != 0) + (m0[i4 + 2] != 0) + (m0[i4 + 3] != 0);
    if (c) atomicAdd(&nz[0], c);
    __syncthreads();
    int fM = (nz[0] == 0);
    int i = b * 256 + tid;
    if (i < NND) {
      unsigned char v = fM ? m0[4 * i] : m0[i];
      emf[i] = 1.f - (float)(v != 0);
    } else {
      int j = i - NND;
      unsigned char v = fM ? m1[4 * j] : m1[j];
      pmf[j] = 1.f - (float)(v != 0);
    }
  } else if (b < nCvt + nBkt) {
    // ---- atomic-free edge bucketing: block-private segments, LDS hist+scan ----
    if (tid == 0) nz[0] = 0;
    hcnt[tid] = 0; hcnt[tid + 256] = 0; hcnt[tid + 512] = 0;
    __syncthreads();
    if (e0[2 * tid + 1] != 0) atomicAdd(&nz[0], 1);
    __syncthreads();
    int fE = (nz[0] == 0);   // int64-format edges
    int e = (b - nCvt) * 256 + tid;
    bool valid = (e < E_);
    int mybid[3]; unsigned int myrec[3]; float myw[3];
    if (valid) {
#pragma unroll
      for (int t = 0; t < 3; ++t) {
        const int* ei = (t == 0) ? e0 : ((t == 1) ? e1 : e2);
        int src = fE ? ei[2 * e] : ei[e];
        int dst = fE ? ei[2 * (E_ + e)] : ei[E_ + e];
        int g = src >> 8, s = src & 255, d = dst & 255;
        mybid[t] = ((g * 3 + t) << 3) | (d >> 5);
        myrec[t] = (unsigned)(((d & 31) << 8) | s);
        myw[t] = (t == 0 ? ew0 : (t == 1 ? ew1 : ew2))[e];
        atomicAdd(&hcnt[mybid[t]], 1u);
      }
    }
    __syncthreads();
    unsigned c0 = hcnt[3 * tid], c1 = hcnt[3 * tid + 1], c2 = hcnt[3 * tid + 2];
    unsigned tsum = c0 + c1 + c2;
    ppart[tid] = tsum;
    __syncthreads();
    for (int off = 1; off < 256; off <<= 1) {
      unsigned v = (tid >= off) ? ppart[tid - off] : 0u;
      __syncthreads();
      ppart[tid] += v;
      __syncthreads();
    }
    unsigned base = ppart[tid] - tsum;   // exclusive prefix
    hoff[3 * tid] = base;
    hoff[3 * tid + 1] = base + c0;
    hoff[3 * tid + 2] = base + c0 + c1;
    __syncthreads();
#pragma unroll
    for (int k = 0; k < 3; ++k) {
      int bin = tid + k * 256;
      unsigned cc = hcnt[bin]; if (cc > 31u) cc = 31u;
      sct[(size_t)(b - nCvt) * 768 + bin] = (u16)(hoff[bin] | (cc << 11));
    }
    __syncthreads();
    if (valid) {
#pragma unroll
      for (int t = 0; t < 3; ++t) {
        unsigned slot = atomicAdd(&hoff[mybid[t]], 1u);
        stage[slot] = make_uint2(myrec[t], __float_as_uint(myw[t]));
      }
    }
    __syncthreads();
    uint2* dstp = &recs[(size_t)(b - nCvt) * 768];
    dstp[tid] = stage[tid];
    dstp[tid + 256] = stage[tid + 256];
    dstp[tid + 512] = stage[tid + 512];
  } else if (b < nCvt + nBkt + 512) {
    int bb = b - nCvt - nBkt;
    int mat = bb >> 6, rem = bb & 63;
    int k0 = (rem >> 3) * 32, n0 = (rem & 7) * 32;
    const float* src = (mat < 6) ? (W + (size_t)mat * 65536) : (T + (size_t)(mat - 6) * 65536);
    int r = tid >> 3, c4 = (tid & 7) * 4;
    const float4 v = *(const float4*)&src[(size_t)(k0 + r) * 256 + n0 + c4];
    tile[r][c4 + 0] = v.x; tile[r][c4 + 1] = v.y; tile[r][c4 + 2] = v.z; tile[r][c4 + 3] = v.w;
    __syncthreads();
    float o[4] = {tile[c4 + 0][r], tile[c4 + 1][r], tile[c4 + 2][r], tile[c4 + 3][r]};
    u16 hh[4], ll[4];
#pragma unroll
    for (int q = 0; q < 4; ++q) split2(o[q], hh[q], ll[q]);
    size_t off = (size_t)mat * 65536 + (size_t)(n0 + r) * 256 + k0 + c4;
    *(ushort4*)&Wth[off] = *(ushort4*)hh;
    *(ushort4*)&Wtl[off] = *(ushort4*)ll;
  } else {
    int bn = b - nCvt - nBkt - 512;    // 0..127
    int n0 = bn * 64;
    int w = tid >> 6, lane = tid & 63;
    for (int it = 0; it < 16; ++it) {
      int nl = it * 4 + w;
      int node = n0 + nl;
      const float4 v = *(const float4*)&x[(size_t)node * 256 + lane * 4];
      u16 hh[4], ll[4];
      split2(v.x, hh[0], ll[0]); split2(v.y, hh[1], ll[1]);
      split2(v.z, hh[2], ll[2]); split2(v.w, hh[3], ll[3]);
      *(ushort4*)&Hh[(size_t)node * 256 + lane * 4] = *(ushort4*)hh;
      *(ushort4*)&Hl[(size_t)node * 256 + lane * 4] = *(ushort4*)ll;
      float s = wave_sum(v.x * v.x + v.y * v.y + v.z * v.z + v.w * v.w);
      if (lane == 0) { float nr = sqrtf(s); nrm[node] = nr; inv[nl] = 1.f / nr; }
    }
    __syncthreads();
    float s = 0.f;
    for (int i = 0; i < 64; ++i) s += x[(size_t)(n0 + i) * 256 + tid] * inv[i];
    Spart[bn * 256 + tid] = s;
  }
}

// ==== stage A (l0, FUSED for intra-dispatch overlap — round-3 lesson):
//      mode0 GEMM l0 (768) | M-build l0 -> bf16 h/l (768) | dinv (128) ====
__global__ __launch_bounds__(256, 2) void k_stageA(
    const u16* __restrict__ Hinh, const u16* __restrict__ Hinl,
    const u16* __restrict__ Wth, const u16* __restrict__ Wtl,
    u16* __restrict__ XWTh, u16* __restrict__ XWTl,
    const u16* __restrict__ sct, const uint2* __restrict__ recs, int nBkt,
    u16* __restrict__ Mbh, u16* __restrict__ Mbl,
    const float* __restrict__ x, const float* __restrict__ Spart,
    const float* __restrict__ nrm, float* __restrict__ dinv) {
  __shared__ u16 lds[LDS_U16];
  const int b = blockIdx.x;
  if (b < 768) {
    mfma_body<0, false>(lds, Hinh, Hinl, Wth, Wtl,
                        nullptr, XWTh, XWTl, nullptr, nullptr, nullptr,
                        b >> 7, b & 127, 0);
  } else if (b < 1536) {
    mbuild_body((float*)lds, b - 768, 0, sct, recs, nBkt, nullptr, Mbh, Mbl);
  } else {
    float* Sl = (float*)lds;
    const int tid = threadIdx.x;
    float s = 0.f;
    for (int bb = 0; bb < 128; ++bb) s += Spart[bb * 256 + tid];
    Sl[tid] = s;
    __syncthreads();
    int base = (b - 1536) * 64;
    int w = tid >> 6, lane = tid & 63;
    const float4 sv = *(const float4*)&Sl[lane * 4];
    for (int it = 0; it < 16; ++it) {
      int node = base + it * 4 + w;
      const float4 v = *(const float4*)&x[(size_t)node * 256 + lane * 4];
      float s2 = wave_sum(v.x * sv.x + v.y * sv.y + v.z * sv.z + v.w * sv.w);
      if (lane == 0) {
        float rowsum = s2 / nrm[node];
        dinv[node] = rsqrtf(fabsf(rowsum) + ZEROF);
      }
    }
  }
}

// ==== k_mbuild (l1 only, standalone — true dependency on post-stageD Abuf) ====
__global__ __launch_bounds__(256, 2) void k_mbuild(
    const u16* __restrict__ sct, const uint2* __restrict__ recs, int nBkt,
    const float* __restrict__ Abuf, u16* __restrict__ Mbh, u16* __restrict__ Mbl) {
  __shared__ float tile[8192];   // 32 KB
  mbuild_body(tile, blockIdx.x, 1, sct, recs, nBkt, Abuf, Mbh, Mbl);
}

// ==== stage B: mode1 (FULL 64x128, first 256 blocks) | (l0 only) mode2 (half, 512) ====
__global__ __launch_bounds__(256, 2) void k_stageB(
    const u16* __restrict__ XWTh, const u16* __restrict__ XWTl,
    const u16* __restrict__ Mbh, const u16* __restrict__ Mbl,
    u16* __restrict__ Houth, u16* __restrict__ Houtl, const float* __restrict__ bias,
    const u16* __restrict__ xh, const u16* __restrict__ xl, float* __restrict__ Abuf,
    const float* __restrict__ nrm, const float* __restrict__ dinv) {
  __shared__ u16 lds[LDS_U16];
  const int b = blockIdx.x;
  if (b < 256) {
    int g = b & 31, r = b >> 5;        // r: 0..7 -> bym 0..3, bxm 0..1
    mfma_body<1, false>(lds, XWTh, XWTl, Mbh, Mbl,
                        nullptr, Houth, Houtl, nullptr, nullptr, bias,
                        r & 1, r >> 1, g);
  } else {
    int bb = b - 256;
    int g = bb & 31, r = bb >> 5;      // r: 0..15 -> bym 0..3, bxm 0..3
    mfma_body<2, true>(lds, xh, xl, xh, xl, Abuf, nullptr, nullptr,
                       nrm, dinv, nullptr, r >> 2, r & 3, g);
  }
}

// ==== stage CA (pack: both depend only on H2): mode4 l0 (512) | mode0 GEMM l1 (768) ====
__global__ __launch_bounds__(256, 2) void k_stageCA(
    const u16* __restrict__ Wth, const u16* __restrict__ Wtl,
    const u16* __restrict__ H2h, const u16* __restrict__ H2l,
    u16* __restrict__ tmph, u16* __restrict__ tmpl,
    u16* __restrict__ XWTh, u16* __restrict__ XWTl) {
  __shared__ u16 lds[LDS_U16];
  const int b = blockIdx.x;
  if (b < 512) {
    // mode4 l0: tmp = H2 @ T_dyn[0]
    mfma_body<4, true>(lds, Wth + (size_t)6 * 65536, Wtl + (size_t)6 * 65536,
                       H2h, H2l, nullptr, tmph, tmpl, nullptr, nullptr, nullptr,
                       b & 127, b >> 7, 0);
  } else {
    // mode0 GEMM l1: XWT_l1 = (H2 @ Wcat_l1)^T
    int bb = b - 512;
    mfma_body<0, false>(lds, H2h, H2l, Wth + (size_t)768 * 256, Wtl + (size_t)768 * 256,
                        nullptr, XWTh, XWTl, nullptr, nullptr, nullptr,
                        bb >> 7, bb & 127, 0);
  }
}

// ============ stage C: mode4 (half, 512): tmp = H @ T (l1 use) ============
__global__ __launch_bounds__(256, 2) void k_stageC(
    const u16* __restrict__ Wth, const u16* __restrict__ Wtl, int l,
    const u16* __restrict__ Hh, const u16* __restrict__ Hl,
    u16* __restrict__ tmph, u16* __restrict__ tmpl) {
  __shared__ u16 lds[LDS_U16];
  const int b = blockIdx.x;
  mfma_body<4, true>(lds, Wth + (size_t)(6 + l) * 65536, Wtl + (size_t)(6 + l) * 65536,
                     Hh, Hl, nullptr, tmph, tmpl, nullptr, nullptr, nullptr,
                     b & 127, b >> 7, 0);
}

// ============ stage D: mode3 (half, 512): A update ============
__global__ __launch_bounds__(256, 2) void k_stageD(
    const u16* __restrict__ tmph, const u16* __restrict__ tmpl,
    const u16* __restrict__ Hh, const u16* __restrict__ Hl,
    float* __restrict__ Abuf) {
  __shared__ u16 lds[LDS_U16];
  const int b = blockIdx.x;
  int g = b & 31, r = b >> 5;
  mfma_body<3, true>(lds, tmph, tmpl, Hh, Hl, Abuf, nullptr, nullptr,
                     nullptr, nullptr, nullptr, r >> 2, r & 3, g);
}

// ============ fused maps ============
__global__ void k_maps(const float* __restrict__ Abuf, const float* __restrict__ emf,
                       const float* __restrict__ pmf, float* __restrict__ out) {
  __shared__ float sme[256], smp[256], red[256];
  const int g = blockIdx.x, tid = threadIdx.x, w = tid >> 6, lane = tid & 63;
  const int j0 = g * 256 + lane * 4;
  const float4 pmv = *(const float4*)&pmf[j0];
  const float4 emv = *(const float4*)&emf[j0];
  for (int it = 0; it < 64; ++it) {
    int nl = it * 4 + w;
    const float4 a = *(const float4*)&Abuf[((size_t)g * 256 + nl) * 256 + lane * 4];
    float me = a.x * pmv.x + a.y * pmv.y + a.z * pmv.z + a.w * pmv.w;
    float mp = a.x * emv.x + a.y * emv.y + a.z * emv.z + a.w * emv.w;
#pragma unroll
    for (int off = 32; off > 0; off >>= 1) {
      me += __shfl_down(me, off, 64);
      mp += __shfl_down(mp, off, 64);
    }
    if (lane == 0) { sme[nl] = me; smp[nl] = mp; }
  }
  __syncthreads();
  for (int which = 0; which < 2; ++which) {
    float v = which ? smp[tid] : sme[tid];
    red[tid] = v; __syncthreads();
    for (int s = 128; s > 0; s >>= 1) { if (tid < s) red[tid] = fminf(red[tid], red[tid + s]); __syncthreads(); }
    float mn = red[0]; __syncthreads();
    red[tid] = v; __syncthreads();
    for (int s = 128; s > 0; s >>= 1) { if (tid < s) red[tid] = fmaxf(red[tid], red[tid + s]); __syncthreads(); }
    float mx = red[0]; __syncthreads();
    float m = (v - mn) / (mx - mn + ZEROF);
    red[tid] = m; __syncthreads();
    for (int s = 128; s > 0; s >>= 1) { if (tid < s) red[tid] += red[tid + s]; __syncthreads(); }
    float sum = red[0]; __syncthreads();
    out[which * NND + g * 256 + tid] = m / (sum + ZEROF);
  }
}

// ================= launch =================
extern "C" void kernel_launch(void* const* d_in, const int* in_sizes, int n_in,
                              void* d_out, int out_size, void* d_ws, size_t ws_size,
                              hipStream_t stream) {
  const float* x = (const float*)d_in[0];
  const unsigned char* em_raw = (const unsigned char*)d_in[7];
  const unsigned char* pm_raw = (const unsigned char*)d_in[8];
  const float* W  = (const float*)d_in[9];
  const float* bg = (const float*)d_in[10];
  const float* T  = (const float*)d_in[11];
  float* out = (float*)d_out;
  const int E_ = in_sizes[2];

  const int nCvt = (2 * NND) / 256;          // 64
  const int nBkt = (E_ + 255) / 256;         // 512 for E=131072

  float* ws = (float*)d_ws;
  size_t o = 0;
  float* Abuf = ws + o; o += (size_t)NND * 256;
  u16* Mbh_l0 = (u16*)(ws + o); o += (size_t)NGRP * 3 * 65536 / 2;
  u16* Mbl_l0 = (u16*)(ws + o); o += (size_t)NGRP * 3 * 65536 / 2;
  u16* Mbh_l1 = (u16*)(ws + o); o += (size_t)NGRP * 3 * 65536 / 2;
  u16* Mbl_l1 = (u16*)(ws + o); o += (size_t)NGRP * 3 * 65536 / 2;
  u16* Hh   = (u16*)(ws + o); o += (size_t)NND * 256 / 2;
  u16* Hl   = (u16*)(ws + o); o += (size_t)NND * 256 / 2;
  u16* H2h  = (u16*)(ws + o); o += (size_t)NND * 256 / 2;
  u16* H2l  = (u16*)(ws + o); o += (size_t)NND * 256 / 2;
  u16* tmph = (u16*)(ws + o); o += (size_t)NND * 256 / 2;
  u16* tmpl = (u16*)(ws + o); o += (size_t)NND * 256 / 2;
  u16* XWTh = (u16*)(ws + o); o += (size_t)768 * NND / 2;
  u16* XWTl = (u16*)(ws + o); o += (size_t)768 * NND / 2;
  u16* Wth  = (u16*)(ws + o); o += (size_t)8 * 65536 / 2;
  u16* Wtl  = (u16*)(ws + o); o += (size_t)8 * 65536 / 2;
  float* nrm   = ws + o; o += NND;
  float* dinv  = ws + o; o += NND;
  float* Spart = ws + o; o += 128 * 256;
  float* emf   = ws + o; o += NND;
  float* pmf   = ws + o; o += NND;
  u16* sct     = (u16*)(ws + o); o += (size_t)nBkt * 768 / 2;
  uint2* recs  = (uint2*)(ws + o); o += (size_t)nBkt * 768 * 2;

  const float* ew0 = (const float*)d_in[2];
  const float* ew1 = (const float*)d_in[4];
  const float* ew2 = (const float*)d_in[6];

  k_prep<<<nCvt + nBkt + 512 + 128, 256, 0, stream>>>(
      (const int*)d_in[1], (const int*)d_in[3], (const int*)d_in[5], em_raw, pm_raw,
      W, T, x, ew0, ew1, ew2, emf, pmf, Wth, Wtl, sct, recs,
      nrm, Spart, Hh, Hl, E_, nCvt, nBkt);

  // ---- layer 0 ----
  k_stageA<<<1664, 256, 0, stream>>>(Hh, Hl, Wth, Wtl, XWTh, XWTl,
                                     sct, recs, nBkt, Mbh_l0, Mbl_l0,
                                     x, Spart, nrm, dinv);
  k_stageB<<<768, 256, 0, stream>>>(XWTh, XWTl, Mbh_l0, Mbl_l0, H2h, H2l, bg,
                                    Hh, Hl, Abuf, nrm, dinv);
  // mode4 l0 + GEMM l1 packed (both depend only on H2)
  k_stageCA<<<1280, 256, 0, stream>>>(Wth, Wtl, H2h, H2l, tmph, tmpl, XWTh, XWTl);
  k_stageD<<<512, 256, 0, stream>>>(tmph, tmpl, H2h, H2l, Abuf);

  // ---- layer 1 ----
  k_mbuild<<<768, 256, 0, stream>>>(sct, recs, nBkt, Abuf, Mbh_l1, Mbl_l1);
  k_stageB<<<256, 256, 0, stream>>>(XWTh, XWTl, Mbh_l1, Mbl_l1, Hh, Hl, bg + 768,
                                    nullptr, nullptr, nullptr, nullptr, nullptr);
  k_stageC<<<512, 256, 0, stream>>>(Wth, Wtl, 1, Hh, Hl, tmph, tmpl);
  k_stageD<<<512, 256, 0, stream>>>(tmph, tmpl, Hh, Hl, Abuf);

  k_maps<<<NGRP, 256, 0, stream>>>(Abuf, emf, pmf, out);
}

// Round 5
// 276.931 us; speedup vs baseline: 1.0817x; 1.0705x over previous
//
#include <hip/hip_runtime.h>

#define NND   8192
#define DDIM  256
#define NGRP  32
#define ZEROF 1e-8f
#define LSTR  40   // K-loop LDS row stride in u16 (80 B: 16B-aligned, 2-way banks free)
#define TSTR  72   // epilogue transpose tile stride in u16 (144 B)
// flat LDS layout (u16 units). TT aliases the B-staging buffers (dead after the
// K-loop, separated by __syncthreads). 32 KB/block.
#define OFF_AH 0
#define OFF_AL 2560
#define OFF_BH 5120
#define OFF_BL 10240
#define OFF_TT 5120          // aliases BH/BL region: 128*72=9216 u16 <= 10240
#define LDS_U16 16384

typedef unsigned short u16;
typedef __attribute__((ext_vector_type(8))) short short8v;
typedef __attribute__((ext_vector_type(4))) float float4v;

__device__ inline u16 f2bf(float x) {
  unsigned u = __float_as_uint(x);
  u += 0x7fffu + ((u >> 16) & 1u);
  return (u16)(u >> 16);
}
__device__ inline float bf2f(u16 h) { return __uint_as_float((unsigned)h << 16); }
__device__ inline void split2(float x, u16& h, u16& l) {
  h = f2bf(x);
  l = f2bf(x - bf2f(h));
}

__device__ inline float wave_sum(float v) {
#pragma unroll
  for (int off = 32; off > 0; off >>= 1) v += __shfl_down(v, off, 64);
  return v;
}

// ================= unified split-bf16 MFMA GEMM body =================
// C-tile 64 x (HALF?64:128), 4 waves, 16x16x32 bf16 MFMA, split-bf16x3.
// MODE 0: XWT[c][node] = (H @ Wcat)^T      a=H(node), b=Wt(c)          [full]
// MODE 1: Hout = relu(b3 + M @ XWcat)      a=XWT(d), b=Mb h/l, K=768   [half, 512 blocks]
// MODE 2: A = (x.xT)*di*dj/(ni*nj+eps)     a=b=x                       [half]
// MODE 3: A = 0.5A + 0.5 sigmoid(t.HT)     a=tmp, b=H                  [half]
// MODE 4: tmp[node][d] = H @ T             a=Tt(d), b=H(node)          [half]
#define LOAD_REGS(tt, kk)                                                                   \
  {                                                                                         \
    int m_ = tid >> 2, kq_ = (tid & 3) * 8;                                                 \
    size_t aoff_;                                                                           \
    if (MODE == 1)                                                                          \
      aoff_ = (size_t)((tt) * 256 + bym * 64 + m_) * 8192 + (size_t)(g * 256 + (kk) + kq_); \
    else if (MODE == 2 || MODE == 3)                                                        \
      aoff_ = (size_t)(g * 256 + bym * 64 + m_) * 256 + (kk) + kq_;                         \
    else                                                                                    \
      aoff_ = (size_t)(bym * 64 + m_) * 256 + (kk) + kq_;                                   \
    rAh = *(const short8v*)&Ah_g[aoff_];                                                    \
    rAl = *(const short8v*)&Al_g[aoff_];                                                    \
    size_t bbase_ = (MODE == 1) ? ((size_t)(g * 3 + (tt)) << 16)                            \
                  : ((MODE == 2 || MODE == 3) ? ((size_t)g << 16) : (size_t)0);             \
    if (HALF) {                                                                             \
      int n_ = tid & 63, kq2_ = (tid >> 6) * 8;                                             \
      size_t boff_ = bbase_ + (size_t)(col0 + n_) * 256 + (kk) + kq2_;                      \
      rBh0 = *(const short8v*)&Bh_g[boff_];                                                 \
      rBl0 = *(const short8v*)&Bl_g[boff_];                                                 \
    } else {                                                                                \
      int n_ = tid & 127, kq2_ = (tid >> 7) * 16;                                           \
      size_t boff_ = bbase_ + (size_t)(col0 + n_) * 256 + (kk) + kq2_;                      \
      rBh0 = *(const short8v*)&Bh_g[boff_]; rBh1 = *(const short8v*)&Bh_g[boff_ + 8];       \
      rBl0 = *(const short8v*)&Bl_g[boff_]; rBl1 = *(const short8v*)&Bl_g[boff_ + 8];       \
    }                                                                                       \
  }

template<int MODE, bool HALF>
__device__ __forceinline__ void mfma_body(
    u16* lds,
    const u16* __restrict__ Ah_g, const u16* __restrict__ Al_g,
    const u16* __restrict__ Bh_g, const u16* __restrict__ Bl_g,
    float* __restrict__ Cf, u16* __restrict__ Ch, u16* __restrict__ Cl,
    const float* __restrict__ nrm, const float* __restrict__ dinv,
    const float* __restrict__ bias,
    int bxm, int bym, int g) {
  u16* Ahs = lds + OFF_AH;
  u16* Als = lds + OFF_AL;
  u16* Bhs = lds + OFF_BH;
  u16* Bls = lds + OFF_BL;
  u16* Tt  = lds + OFF_TT;    // aliases Bhs/Bls — only used after K-loop + sync
  const int NJ = HALF ? 2 : 4;
  const int tid = threadIdx.x;
  const int col0 = bxm * (HALF ? 64 : 128);
  const int w = tid >> 6, lane = tid & 63;
  const int lm = lane & 15, lq = lane >> 4;
  const int wr = (w >> 1) * 32, wc = (w & 1) * (HALF ? 32 : 64);

  float4v acc[2][4];
#pragma unroll
  for (int i = 0; i < 2; ++i)
#pragma unroll
    for (int j = 0; j < NJ; ++j) acc[i][j] = (float4v)0.f;

  short8v rAh, rAl, rBh0, rBh1, rBl0, rBl1;
  const int TOTAL = (MODE == 1) ? 24 : 8;

  LOAD_REGS(0, 0);
  for (int step = 0; step < TOTAL; ++step) {
    if (step) __syncthreads();
    {
      int m = tid >> 2, kq = (tid & 3) * 8;
      *(short8v*)&Ahs[m * LSTR + kq] = rAh;
      *(short8v*)&Als[m * LSTR + kq] = rAl;
    }
    if (HALF) {
      int n = tid & 63, kq2 = (tid >> 6) * 8;
      *(short8v*)&Bhs[n * LSTR + kq2] = rBh0;
      *(short8v*)&Bls[n * LSTR + kq2] = rBl0;
    } else {
      int n = tid & 127, kq2 = (tid >> 7) * 16;
      *(short8v*)&Bhs[n * LSTR + kq2] = rBh0; *(short8v*)&Bhs[n * LSTR + kq2 + 8] = rBh1;
      *(short8v*)&Bls[n * LSTR + kq2] = rBl0; *(short8v*)&Bls[n * LSTR + kq2 + 8] = rBl1;
    }
    // Hoisted BEFORE the barrier: next-step global loads are in flight during the
    // barrier drain + ds_read + MFMA (regs already flushed to LDS above; hazards
    // still guarded by the two barriers). Compiler can't move loads across
    // __syncthreads itself.
    int nxt = step + 1;
    if (nxt < TOTAL) {
      int tt = nxt >> 3, kk = (nxt & 7) * 32;
      LOAD_REGS(tt, kk);
    }
    __syncthreads();
    short8v ah[2], al[2], bh[4], bl[4];
#pragma unroll
    for (int i = 0; i < 2; ++i) {
      int r = wr + i * 16 + lm;
      ah[i] = *(const short8v*)&Ahs[r * LSTR + lq * 8];
      al[i] = *(const short8v*)&Als[r * LSTR + lq * 8];
    }
#pragma unroll
    for (int j = 0; j < NJ; ++j) {
      int r = wc + j * 16 + lm;
      bh[j] = *(const short8v*)&Bhs[r * LSTR + lq * 8];
      bl[j] = *(const short8v*)&Bls[r * LSTR + lq * 8];
    }
#pragma unroll
    for (int i = 0; i < 2; ++i)
#pragma unroll
      for (int j = 0; j < NJ; ++j) {
        acc[i][j] = __builtin_amdgcn_mfma_f32_16x16x32_bf16(ah[i], bh[j], acc[i][j], 0, 0, 0);
        acc[i][j] = __builtin_amdgcn_mfma_f32_16x16x32_bf16(ah[i], bl[j], acc[i][j], 0, 0, 0);
        acc[i][j] = __builtin_amdgcn_mfma_f32_16x16x32_bf16(al[i], bh[j], acc[i][j], 0, 0, 0);
      }
  }

  // ---- epilogues (frag: col=lm, row=lq*4+r) ----
  if (MODE == 2 || MODE == 3) {
#pragma unroll
    for (int i = 0; i < 2; ++i) {
#pragma unroll
      for (int r = 0; r < 4; ++r) {
        int grow = g * 256 + bym * 64 + wr + i * 16 + lq * 4 + r;
        float di = 0.f, ni = 0.f;
        if (MODE == 2) { di = dinv[grow]; ni = nrm[grow]; }
#pragma unroll
        for (int j = 0; j < NJ; ++j) {
          int gcol = col0 + wc + j * 16 + lm;
          size_t ci = (size_t)grow * 256 + gcol;
          float v = acc[i][j][r];
          if (MODE == 2) {
            int gj = g * 256 + gcol;
            Cf[ci] = v * di * dinv[gj] / (ni * nrm[gj] + ZEROF);
          } else {
            Cf[ci] = 0.5f * Cf[ci] + 0.5f * (1.f / (1.f + expf(-v)));
          }
        }
      }
    }
  } else {
    float bsum[8];
    if (MODE == 1) {
#pragma unroll
      for (int i = 0; i < 2; ++i)
#pragma unroll
        for (int r = 0; r < 4; ++r) {
          int d = bym * 64 + wr + i * 16 + lq * 4 + r;
          bsum[i * 4 + r] = bias[d] + bias[256 + d] + bias[512 + d];
        }
    }
    u16 hv[32], lv[32];
#pragma unroll
    for (int i = 0; i < 2; ++i)
#pragma unroll
      for (int j = 0; j < NJ; ++j)
#pragma unroll
        for (int r = 0; r < 4; ++r) {
          float v = acc[i][j][r];
          if (MODE == 1) v = fmaxf(v + bsum[i * 4 + r], 0.f);
          split2(v, hv[(i * 4 + r) * NJ + j], lv[(i * 4 + r) * NJ + j]);
        }
    int ebase1 = (MODE == 1) ? (g * 256 + col0) : col0;
    int ebase2 = bym * 64;
    size_t estride = (MODE == 0) ? 8192 : 256;
#pragma unroll
    for (int ph = 0; ph < 2; ++ph) {
      __syncthreads();
      const u16* sv = ph ? lv : hv;
#pragma unroll
      for (int i = 0; i < 2; ++i)
#pragma unroll
        for (int j = 0; j < NJ; ++j)
#pragma unroll
          for (int r = 0; r < 4; ++r)
            Tt[(wc + j * 16 + lm) * TSTR + wr + i * 16 + lq * 4 + r] = sv[(i * 4 + r) * NJ + j];
      __syncthreads();
      u16* dst = ph ? Cl : Ch;
      int cc0 = tid >> 3, mm0 = (tid & 7) * 8;
#pragma unroll
      for (int it = 0; it < (HALF ? 2 : 4); ++it) {
        int cc = it * 32 + cc0;
        short8v v = *(const short8v*)&Tt[cc * TSTR + mm0];
        *(short8v*)&dst[(size_t)(ebase1 + cc) * estride + ebase2 + mm0] = v;
      }
    }
  }
}

// ---- M-build block body: dense 32x256 fp32 tile from buckets -> bf16 h/l ----
__device__ __forceinline__ void mbuild_body(
    float* tile, int bid, int l,
    const u16* __restrict__ sct, const uint2* __restrict__ recs, int nBkt,
    const float* __restrict__ Abuf, u16* __restrict__ Mbh, u16* __restrict__ Mbl) {
  const int tid = threadIdx.x;
  int gt = bid >> 3, chunk = bid & 7;
  int g = gt / 3;
  float4 z = make_float4(0.f, 0.f, 0.f, 0.f);
#pragma unroll
  for (int k = 0; k < 8; ++k) ((float4*)tile)[k * 256 + tid] = z;
  __syncthreads();
  for (int bb = tid; bb < nBkt; bb += 256) {
    unsigned sc = sct[(size_t)bb * 768 + bid];
    unsigned start = sc & 2047u, cnt = sc >> 11;
    const uint2* rp = &recs[(size_t)bb * 768 + start];
    for (unsigned k = 0; k < cnt; ++k) {
      uint2 r = rp[k];
      int s = r.x & 255, d5 = (r.x >> 8) & 31;
      float w = l ? Abuf[(size_t)(g * 256 + s) * 256 + chunk * 32 + d5]
                  : __uint_as_float(r.y);
      atomicAdd(&tile[d5 * 256 + s], w);
    }
  }
  __syncthreads();
  size_t base4 = ((size_t)gt << 14) + ((size_t)chunk << 11);  // ushort4 units
#pragma unroll
  for (int k = 0; k < 8; ++k) {
    float4 f = ((float4*)tile)[k * 256 + tid];
    ushort4 h, lo;
    split2(f.x, h.x, lo.x); split2(f.y, h.y, lo.y);
    split2(f.z, h.z, lo.z); split2(f.w, h.w, lo.w);
    ((ushort4*)Mbh)[base4 + k * 256 + tid] = h;
    ((ushort4*)Mbl)[base4 + k * 256 + tid] = lo;
  }
}

// ===== prep: mask cvt | edge bucketing (atomic-free) | transpose/split W | norms+x-split =====
__global__ void k_prep(const int* __restrict__ e0, const int* __restrict__ e1,
                       const int* __restrict__ e2, const unsigned char* __restrict__ m0,
                       const unsigned char* __restrict__ m1,
                       const float* __restrict__ W, const float* __restrict__ T,
                       const float* __restrict__ x,
                       const float* __restrict__ ew0, const float* __restrict__ ew1,
                       const float* __restrict__ ew2,
                       float* __restrict__ emf, float* __restrict__ pmf,
                       u16* __restrict__ Wth, u16* __restrict__ Wtl,
                       u16* __restrict__ sct, uint2* __restrict__ recs,
                       float* __restrict__ nrm, float* __restrict__ Spart,
                       u16* __restrict__ Hh, u16* __restrict__ Hl,
                       int E_, int nCvt, int nBkt) {
  __shared__ float tile[32][33];
  __shared__ float inv[64];
  __shared__ int nz[1];
  __shared__ unsigned int hcnt[768];
  __shared__ unsigned int hoff[768];
  __shared__ unsigned int ppart[256];
  __shared__ uint2 stage[768];
  const int b = blockIdx.x, tid = threadIdx.x;
  if (b < nCvt) {
    // ---- mask dtype detect + convert (2*NND values) ----
    if (tid == 0) nz[0] = 0;
    __syncthreads();
    int i4 = tid * 4;
    int c = (m0[i4 + 1] != 0) + (m0[i4 + 2] != 0) + (m0[i4 + 3] != 0);
    if (c) atomicAdd(&nz[0], c);
    __syncthreads();
    int fM = (nz[0] == 0);
    int i = b * 256 + tid;
    if (i < NND) {
      unsigned char v = fM ? m0[4 * i] : m0[i];
      emf[i] = 1.f - (float)(v != 0);
    } else {
      int j = i - NND;
      unsigned char v = fM ? m1[4 * j] : m1[j];
      pmf[j] = 1.f - (float)(v != 0);
    }
  } else if (b < nCvt + nBkt) {
    // ---- atomic-free edge bucketing: block-private segments, LDS hist+scan ----
    if (tid == 0) nz[0] = 0;
    hcnt[tid] = 0; hcnt[tid + 256] = 0; hcnt[tid + 512] = 0;
    __syncthreads();
    if (e0[2 * tid + 1] != 0) atomicAdd(&nz[0], 1);
    __syncthreads();
    int fE = (nz[0] == 0);   // int64-format edges
    int e = (b - nCvt) * 256 + tid;
    bool valid = (e < E_);
    int mybid[3]; unsigned int myrec[3]; float myw[3];
    if (valid) {
#pragma unroll
      for (int t = 0; t < 3; ++t) {
        const int* ei = (t == 0) ? e0 : ((t == 1) ? e1 : e2);
        int src = fE ? ei[2 * e] : ei[e];
        int dst = fE ? ei[2 * (E_ + e)] : ei[E_ + e];
        int g = src >> 8, s = src & 255, d = dst & 255;
        mybid[t] = ((g * 3 + t) << 3) | (d >> 5);
        myrec[t] = (unsigned)(((d & 31) << 8) | s);
        myw[t] = (t == 0 ? ew0 : (t == 1 ? ew1 : ew2))[e];
        atomicAdd(&hcnt[mybid[t]], 1u);
      }
    }
    __syncthreads();
    unsigned c0 = hcnt[3 * tid], c1 = hcnt[3 * tid + 1], c2 = hcnt[3 * tid + 2];
    unsigned tsum = c0 + c1 + c2;
    ppart[tid] = tsum;
    __syncthreads();
    for (int off = 1; off < 256; off <<= 1) {
      unsigned v = (tid >= off) ? ppart[tid - off] : 0u;
      __syncthreads();
      ppart[tid] += v;
      __syncthreads();
    }
    unsigned base = ppart[tid] - tsum;   // exclusive prefix
    hoff[3 * tid] = base;
    hoff[3 * tid + 1] = base + c0;
    hoff[3 * tid + 2] = base + c0 + c1;
    __syncthreads();
#pragma unroll
    for (int k = 0; k < 3; ++k) {
      int bin = tid + k * 256;
      unsigned cc = hcnt[bin]; if (cc > 31u) cc = 31u;
      sct[(size_t)(b - nCvt) * 768 + bin] = (u16)(hoff[bin] | (cc << 11));
    }
    __syncthreads();
    if (valid) {
#pragma unroll
      for (int t = 0; t < 3; ++t) {
        unsigned slot = atomicAdd(&hoff[mybid[t]], 1u);
        stage[slot] = make_uint2(myrec[t], __float_as_uint(myw[t]));
      }
    }
    __syncthreads();
    uint2* dstp = &recs[(size_t)(b - nCvt) * 768];
    dstp[tid] = stage[tid];
    dstp[tid + 256] = stage[tid + 256];
    dstp[tid + 512] = stage[tid + 512];
  } else if (b < nCvt + nBkt + 512) {
    int bb = b - nCvt - nBkt;
    int mat = bb >> 6, rem = bb & 63;
    int k0 = (rem >> 3) * 32, n0 = (rem & 7) * 32;
    const float* src = (mat < 6) ? (W + (size_t)mat * 65536) : (T + (size_t)(mat - 6) * 65536);
    int r = tid >> 3, c4 = (tid & 7) * 4;
    const float4 v = *(const float4*)&src[(size_t)(k0 + r) * 256 + n0 + c4];
    tile[r][c4 + 0] = v.x; tile[r][c4 + 1] = v.y; tile[r][c4 + 2] = v.z; tile[r][c4 + 3] = v.w;
    __syncthreads();
    float o[4] = {tile[c4 + 0][r], tile[c4 + 1][r], tile[c4 + 2][r], tile[c4 + 3][r]};
    u16 hh[4], ll[4];
#pragma unroll
    for (int q = 0; q < 4; ++q) split2(o[q], hh[q], ll[q]);
    size_t off = (size_t)mat * 65536 + (size_t)(n0 + r) * 256 + k0 + c4;
    *(ushort4*)&Wth[off] = *(ushort4*)hh;
    *(ushort4*)&Wtl[off] = *(ushort4*)ll;
  } else {
    int bn = b - nCvt - nBkt - 512;    // 0..127
    int n0 = bn * 64;
    int w = tid >> 6, lane = tid & 63;
    for (int it = 0; it < 16; ++it) {
      int nl = it * 4 + w;
      int node = n0 + nl;
      const float4 v = *(const float4*)&x[(size_t)node * 256 + lane * 4];
      u16 hh[4], ll[4];
      split2(v.x, hh[0], ll[0]); split2(v.y, hh[1], ll[1]);
      split2(v.z, hh[2], ll[2]); split2(v.w, hh[3], ll[3]);
      *(ushort4*)&Hh[(size_t)node * 256 + lane * 4] = *(ushort4*)hh;
      *(ushort4*)&Hl[(size_t)node * 256 + lane * 4] = *(ushort4*)ll;
      float s = wave_sum(v.x * v.x + v.y * v.y + v.z * v.z + v.w * v.w);
      if (lane == 0) { float nr = sqrtf(s); nrm[node] = nr; inv[nl] = 1.f / nr; }
    }
    __syncthreads();
    float s = 0.f;
    for (int i = 0; i < 64; ++i) s += x[(size_t)(n0 + i) * 256 + tid] * inv[i];
    Spart[bn * 256 + tid] = s;
  }
}

// ==== stage A (l0, fused heterogeneous pack — round-3 lesson):
//      mode0 GEMM l0 (768) | M-build l0 -> bf16 h/l (768) | dinv (128) ====
__global__ __launch_bounds__(256, 2) void k_stageA(
    const u16* __restrict__ Hinh, const u16* __restrict__ Hinl,
    const u16* __restrict__ Wth, const u16* __restrict__ Wtl,
    u16* __restrict__ XWTh, u16* __restrict__ XWTl,
    const u16* __restrict__ sct, const uint2* __restrict__ recs, int nBkt,
    u16* __restrict__ Mbh, u16* __restrict__ Mbl,
    const float* __restrict__ x, const float* __restrict__ Spart,
    const float* __restrict__ nrm, float* __restrict__ dinv) {
  __shared__ u16 lds[LDS_U16];
  const int b = blockIdx.x;
  if (b < 768) {
    mfma_body<0, false>(lds, Hinh, Hinl, Wth, Wtl,
                        nullptr, XWTh, XWTl, nullptr, nullptr, nullptr,
                        b >> 7, b & 127, 0);
  } else if (b < 1536) {
    mbuild_body((float*)lds, b - 768, 0, sct, recs, nBkt, nullptr, Mbh, Mbl);
  } else {
    float* Sl = (float*)lds;
    const int tid = threadIdx.x;
    float s = 0.f;
    for (int bb = 0; bb < 128; ++bb) s += Spart[bb * 256 + tid];
    Sl[tid] = s;
    __syncthreads();
    int base = (b - 1536) * 64;
    int w = tid >> 6, lane = tid & 63;
    const float4 sv = *(const float4*)&Sl[lane * 4];
    for (int it = 0; it < 16; ++it) {
      int node = base + it * 4 + w;
      const float4 v = *(const float4*)&x[(size_t)node * 256 + lane * 4];
      float s2 = wave_sum(v.x * sv.x + v.y * sv.y + v.z * sv.z + v.w * sv.w);
      if (lane == 0) {
        float rowsum = s2 / nrm[node];
        dinv[node] = rsqrtf(fabsf(rowsum) + ZEROF);
      }
    }
  }
}

// ==== stage A2 (l1, fused heterogeneous pack): mode0 GEMM l1 (768) | M-build l1 (768) ====
__global__ __launch_bounds__(256, 2) void k_stageA2(
    const u16* __restrict__ H2h, const u16* __restrict__ H2l,
    const u16* __restrict__ Wth, const u16* __restrict__ Wtl,
    u16* __restrict__ XWTh, u16* __restrict__ XWTl,
    const u16* __restrict__ sct, const uint2* __restrict__ recs, int nBkt,
    const float* __restrict__ Abuf,
    u16* __restrict__ Mbh, u16* __restrict__ Mbl) {
  __shared__ u16 lds[LDS_U16];
  const int b = blockIdx.x;
  if (b < 768) {
    mfma_body<0, false>(lds, H2h, H2l, Wth + (size_t)768 * 256, Wtl + (size_t)768 * 256,
                        nullptr, XWTh, XWTl, nullptr, nullptr, nullptr,
                        b >> 7, b & 127, 0);
  } else {
    mbuild_body((float*)lds, b - 768, 1, sct, recs, nBkt, Abuf, Mbh, Mbl);
  }
}

// ==== stage B: mode1 (HALF 64x64, 512 blocks) | (l0 only) mode2 (half, 512) ====
__global__ __launch_bounds__(256, 2) void k_stageB(
    const u16* __restrict__ XWTh, const u16* __restrict__ XWTl,
    const u16* __restrict__ Mbh, const u16* __restrict__ Mbl,
    u16* __restrict__ Houth, u16* __restrict__ Houtl, const float* __restrict__ bias,
    const u16* __restrict__ xh, const u16* __restrict__ xl, float* __restrict__ Abuf,
    const float* __restrict__ nrm, const float* __restrict__ dinv) {
  __shared__ u16 lds[LDS_U16];
  const int b = blockIdx.x;
  if (b < 512) {
    int g = b & 31, r = b >> 5;        // r: 0..15 -> bxm 0..3, bym 0..3
    mfma_body<1, true>(lds, XWTh, XWTl, Mbh, Mbl,
                       nullptr, Houth, Houtl, nullptr, nullptr, bias,
                       r >> 2, r & 3, g);
  } else {
    int bb = b - 512;
    int g = bb & 31, r = bb >> 5;      // r: 0..15 -> bxm 0..3, bym 0..3
    mfma_body<2, true>(lds, xh, xl, xh, xl, Abuf, nullptr, nullptr,
                       nrm, dinv, nullptr, r >> 2, r & 3, g);
  }
}

// ============ stage C: mode4 (half, 512): tmp = H @ T ============
__global__ __launch_bounds__(256, 2) void k_stageC(
    const u16* __restrict__ Wth, const u16* __restrict__ Wtl, int l,
    const u16* __restrict__ Hh, const u16* __restrict__ Hl,
    u16* __restrict__ tmph, u16* __restrict__ tmpl) {
  __shared__ u16 lds[LDS_U16];
  const int b = blockIdx.x;
  mfma_body<4, true>(lds, Wth + (size_t)(6 + l) * 65536, Wtl + (size_t)(6 + l) * 65536,
                     Hh, Hl, nullptr, tmph, tmpl, nullptr, nullptr, nullptr,
                     b & 127, b >> 7, 0);
}

// ============ stage D: mode3 (half, 512): A update ============
__global__ __launch_bounds__(256, 2) void k_stageD(
    const u16* __restrict__ tmph, const u16* __restrict__ tmpl,
    const u16* __restrict__ Hh, const u16* __restrict__ Hl,
    float* __restrict__ Abuf) {
  __shared__ u16 lds[LDS_U16];
  const int b = blockIdx.x;
  int g = b & 31, r = b >> 5;
  mfma_body<3, true>(lds, tmph, tmpl, Hh, Hl, Abuf, nullptr, nullptr,
                     nullptr, nullptr, nullptr, r >> 2, r & 3, g);
}

// ============ fused maps ============
__global__ void k_maps(const float* __restrict__ Abuf, const float* __restrict__ emf,
                       const float* __restrict__ pmf, float* __restrict__ out) {
  __shared__ float sme[256], smp[256], red[256];
  const int g = blockIdx.x, tid = threadIdx.x, w = tid >> 6, lane = tid & 63;
  const int j0 = g * 256 + lane * 4;
  const float4 pmv = *(const float4*)&pmf[j0];
  const float4 emv = *(const float4*)&emf[j0];
  for (int it = 0; it < 64; ++it) {
    int nl = it * 4 + w;
    const float4 a = *(const float4*)&Abuf[((size_t)g * 256 + nl) * 256 + lane * 4];
    float me = a.x * pmv.x + a.y * pmv.y + a.z * pmv.z + a.w * pmv.w;
    float mp = a.x * emv.x + a.y * emv.y + a.z * emv.z + a.w * emv.w;
#pragma unroll
    for (int off = 32; off > 0; off >>= 1) {
      me += __shfl_down(me, off, 64);
      mp += __shfl_down(mp, off, 64);
    }
    if (lane == 0) { sme[nl] = me; smp[nl] = mp; }
  }
  __syncthreads();
  for (int which = 0; which < 2; ++which) {
    float v = which ? smp[tid] : sme[tid];
    red[tid] = v; __syncthreads();
    for (int s = 128; s > 0; s >>= 1) { if (tid < s) red[tid] = fminf(red[tid], red[tid + s]); __syncthreads(); }
    float mn = red[0]; __syncthreads();
    red[tid] = v; __syncthreads();
    for (int s = 128; s > 0; s >>= 1) { if (tid < s) red[tid] = fmaxf(red[tid], red[tid + s]); __syncthreads(); }
    float mx = red[0]; __syncthreads();
    float m = (v - mn) / (mx - mn + ZEROF);
    red[tid] = m; __syncthreads();
    for (int s = 128; s > 0; s >>= 1) { if (tid < s) red[tid] += red[tid + s]; __syncthreads(); }
    float sum = red[0]; __syncthreads();
    out[which * NND + g * 256 + tid] = m / (sum + ZEROF);
  }
}

// ================= launch =================
extern "C" void kernel_launch(void* const* d_in, const int* in_sizes, int n_in,
                              void* d_out, int out_size, void* d_ws, size_t ws_size,
                              hipStream_t stream) {
  const float* x = (const float*)d_in[0];
  const unsigned char* em_raw = (const unsigned char*)d_in[7];
  const unsigned char* pm_raw = (const unsigned char*)d_in[8];
  const float* W  = (const float*)d_in[9];
  const float* bg = (const float*)d_in[10];
  const float* T  = (const float*)d_in[11];
  float* out = (float*)d_out;
  const int E_ = in_sizes[2];

  const int nCvt = (2 * NND) / 256;          // 64
  const int nBkt = (E_ + 255) / 256;         // 512 for E=131072

  float* ws = (float*)d_ws;
  size_t o = 0;
  float* Abuf = ws + o; o += (size_t)NND * 256;
  u16* Mbh_l0 = (u16*)(ws + o); o += (size_t)NGRP * 3 * 65536 / 2;
  u16* Mbl_l0 = (u16*)(ws + o); o += (size_t)NGRP * 3 * 65536 / 2;
  u16* Mbh_l1 = (u16*)(ws + o); o += (size_t)NGRP * 3 * 65536 / 2;
  u16* Mbl_l1 = (u16*)(ws + o); o += (size_t)NGRP * 3 * 65536 / 2;
  u16* Hh   = (u16*)(ws + o); o += (size_t)NND * 256 / 2;
  u16* Hl   = (u16*)(ws + o); o += (size_t)NND * 256 / 2;
  u16* H2h  = (u16*)(ws + o); o += (size_t)NND * 256 / 2;
  u16* H2l  = (u16*)(ws + o); o += (size_t)NND * 256 / 2;
  u16* tmph = (u16*)(ws + o); o += (size_t)NND * 256 / 2;
  u16* tmpl = (u16*)(ws + o); o += (size_t)NND * 256 / 2;
  u16* XWTh = (u16*)(ws + o); o += (size_t)768 * NND / 2;
  u16* XWTl = (u16*)(ws + o); o += (size_t)768 * NND / 2;
  u16* Wth  = (u16*)(ws + o); o += (size_t)8 * 65536 / 2;
  u16* Wtl  = (u16*)(ws + o); o += (size_t)8 * 65536 / 2;
  float* nrm   = ws + o; o += NND;
  float* dinv  = ws + o; o += NND;
  float* Spart = ws + o; o += 128 * 256;
  float* emf   = ws + o; o += NND;
  float* pmf   = ws + o; o += NND;
  u16* sct     = (u16*)(ws + o); o += (size_t)nBkt * 768 / 2;
  uint2* recs  = (uint2*)(ws + o); o += (size_t)nBkt * 768 * 2;

  const float* ew0 = (const float*)d_in[2];
  const float* ew1 = (const float*)d_in[4];
  const float* ew2 = (const float*)d_in[6];

  k_prep<<<nCvt + nBkt + 512 + 128, 256, 0, stream>>>(
      (const int*)d_in[1], (const int*)d_in[3], (const int*)d_in[5], em_raw, pm_raw,
      W, T, x, ew0, ew1, ew2, emf, pmf, Wth, Wtl, sct, recs,
      nrm, Spart, Hh, Hl, E_, nCvt, nBkt);

  // ---- layer 0 ----
  k_stageA<<<1664, 256, 0, stream>>>(Hh, Hl, Wth, Wtl, XWTh, XWTl,
                                     sct, recs, nBkt, Mbh_l0, Mbl_l0,
                                     x, Spart, nrm, dinv);
  k_stageB<<<1024, 256, 0, stream>>>(XWTh, XWTl, Mbh_l0, Mbl_l0, H2h, H2l, bg,
                                     Hh, Hl, Abuf, nrm, dinv);
  k_stageC<<<512, 256, 0, stream>>>(Wth, Wtl, 0, H2h, H2l, tmph, tmpl);
  k_stageD<<<512, 256, 0, stream>>>(tmph, tmpl, H2h, H2l, Abuf);

  // ---- layer 1 ----
  k_stageA2<<<1536, 256, 0, stream>>>(H2h, H2l, Wth, Wtl, XWTh, XWTl,
                                      sct, recs, nBkt, Abuf, Mbh_l1, Mbl_l1);
  k_stageB<<<512, 256, 0, stream>>>(XWTh, XWTl, Mbh_l1, Mbl_l1, Hh, Hl, bg + 768,
                                    nullptr, nullptr, nullptr, nullptr, nullptr);
  k_stageC<<<512, 256, 0, stream>>>(Wth, Wtl, 1, Hh, Hl, tmph, tmpl);
  k_stageD<<<512, 256, 0, stream>>>(tmph, tmpl, Hh, Hl, Abuf);

  k_maps<<<NGRP, 256, 0, stream>>>(Abuf, emf, pmf, out);
}

// Round 6
// 274.568 us; speedup vs baseline: 1.0911x; 1.0086x over previous
//
#include <hip/hip_runtime.h>

#define NND   8192
#define DDIM  256
#define NGRP  32
#define ZEROF 1e-8f
#define LSTR  40   // K-loop LDS row stride in u16 (80 B: 16B-aligned, 2-way banks free)
#define TSTR  72   // epilogue transpose tile stride in u16 (144 B)
// flat LDS layout (u16 units). TT aliases the B-staging buffers (dead after the
// K-loop, separated by __syncthreads). 32 KB/block.
#define OFF_AH 0
#define OFF_AL 2560
#define OFF_BH 5120
#define OFF_BL 10240
#define OFF_TT 5120          // aliases BH/BL region: 128*72=9216 u16 <= 10240
#define LDS_U16 16384

typedef unsigned short u16;
typedef __attribute__((ext_vector_type(8))) short short8v;
typedef __attribute__((ext_vector_type(4))) float float4v;

__device__ inline u16 f2bf(float x) {
  unsigned u = __float_as_uint(x);
  u += 0x7fffu + ((u >> 16) & 1u);
  return (u16)(u >> 16);
}
__device__ inline float bf2f(u16 h) { return __uint_as_float((unsigned)h << 16); }
__device__ inline void split2(float x, u16& h, u16& l) {
  h = f2bf(x);
  l = f2bf(x - bf2f(h));
}

__device__ inline float wave_sum(float v) {
#pragma unroll
  for (int off = 32; off > 0; off >>= 1) v += __shfl_down(v, off, 64);
  return v;
}

// ================= unified split-bf16 MFMA GEMM body =================
// C-tile 64 x (HALF?64:128), 4 waves, 16x16x32 bf16 MFMA, split-bf16x3.
// MODE 0: XWT[c][node] = (H @ Wcat)^T       a=H(node), b=Wt(c)          [full]
// MODE 1: Hout = relu(b3 + M @ XWcat)       a=XWT(d), b=Mb h/l, K=768   [half]
// MODE 2: A_raw = x.xT (UNSCALED)           a=b=x                       [half]
// MODE 3: A = 0.5A + 0.5 sigmoid(t.HT)      a=tmp, b=H                  [half]
// MODE 5: A = 0.5*A_raw*scale + 0.5 sig(.)  a=tmp, b=H; scale=di*dj/(ni*nj+e) [half]
// MODE 4: tmp[node][d] = H @ T              a=Tt(d), b=H(node)          [half]
// NOTE (round-5 lesson): LOAD_REGS for step k+1 issues AFTER the second barrier
// (round-2 order). Hoisting before the barrier costs +12 VGPR, occupancy 24->19%,
// stageA +5us — measured regression.
#define LOAD_REGS(tt, kk)                                                                   \
  {                                                                                         \
    int m_ = tid >> 2, kq_ = (tid & 3) * 8;                                                 \
    size_t aoff_;                                                                           \
    if (MODE == 1)                                                                          \
      aoff_ = (size_t)((tt) * 256 + bym * 64 + m_) * 8192 + (size_t)(g * 256 + (kk) + kq_); \
    else if (MODE == 2 || MODE == 3 || MODE == 5)                                           \
      aoff_ = (size_t)(g * 256 + bym * 64 + m_) * 256 + (kk) + kq_;                         \
    else                                                                                    \
      aoff_ = (size_t)(bym * 64 + m_) * 256 + (kk) + kq_;                                   \
    rAh = *(const short8v*)&Ah_g[aoff_];                                                    \
    rAl = *(const short8v*)&Al_g[aoff_];                                                    \
    size_t bbase_ = (MODE == 1) ? ((size_t)(g * 3 + (tt)) << 16)                            \
                  : ((MODE == 2 || MODE == 3 || MODE == 5) ? ((size_t)g << 16) : (size_t)0);\
    if (HALF) {                                                                             \
      int n_ = tid & 63, kq2_ = (tid >> 6) * 8;                                             \
      size_t boff_ = bbase_ + (size_t)(col0 + n_) * 256 + (kk) + kq2_;                      \
      rBh0 = *(const short8v*)&Bh_g[boff_];                                                 \
      rBl0 = *(const short8v*)&Bl_g[boff_];                                                 \
    } else {                                                                                \
      int n_ = tid & 127, kq2_ = (tid >> 7) * 16;                                           \
      size_t boff_ = bbase_ + (size_t)(col0 + n_) * 256 + (kk) + kq2_;                      \
      rBh0 = *(const short8v*)&Bh_g[boff_]; rBh1 = *(const short8v*)&Bh_g[boff_ + 8];       \
      rBl0 = *(const short8v*)&Bl_g[boff_]; rBl1 = *(const short8v*)&Bl_g[boff_ + 8];       \
    }                                                                                       \
  }

template<int MODE, bool HALF>
__device__ __forceinline__ void mfma_body(
    u16* lds,
    const u16* __restrict__ Ah_g, const u16* __restrict__ Al_g,
    const u16* __restrict__ Bh_g, const u16* __restrict__ Bl_g,
    float* __restrict__ Cf, u16* __restrict__ Ch, u16* __restrict__ Cl,
    const float* __restrict__ nrm, const float* __restrict__ dinv,
    const float* __restrict__ bias,
    int bxm, int bym, int g) {
  u16* Ahs = lds + OFF_AH;
  u16* Als = lds + OFF_AL;
  u16* Bhs = lds + OFF_BH;
  u16* Bls = lds + OFF_BL;
  u16* Tt  = lds + OFF_TT;    // aliases Bhs/Bls — only used after K-loop + sync
  const int NJ = HALF ? 2 : 4;
  const int tid = threadIdx.x;
  const int col0 = bxm * (HALF ? 64 : 128);
  const int w = tid >> 6, lane = tid & 63;
  const int lm = lane & 15, lq = lane >> 4;
  const int wr = (w >> 1) * 32, wc = (w & 1) * (HALF ? 32 : 64);

  float4v acc[2][4];
#pragma unroll
  for (int i = 0; i < 2; ++i)
#pragma unroll
    for (int j = 0; j < NJ; ++j) acc[i][j] = (float4v)0.f;

  short8v rAh, rAl, rBh0, rBh1, rBl0, rBl1;
  const int TOTAL = (MODE == 1) ? 24 : 8;

  LOAD_REGS(0, 0);
  for (int step = 0; step < TOTAL; ++step) {
    if (step) __syncthreads();
    {
      int m = tid >> 2, kq = (tid & 3) * 8;
      *(short8v*)&Ahs[m * LSTR + kq] = rAh;
      *(short8v*)&Als[m * LSTR + kq] = rAl;
    }
    if (HALF) {
      int n = tid & 63, kq2 = (tid >> 6) * 8;
      *(short8v*)&Bhs[n * LSTR + kq2] = rBh0;
      *(short8v*)&Bls[n * LSTR + kq2] = rBl0;
    } else {
      int n = tid & 127, kq2 = (tid >> 7) * 16;
      *(short8v*)&Bhs[n * LSTR + kq2] = rBh0; *(short8v*)&Bhs[n * LSTR + kq2 + 8] = rBh1;
      *(short8v*)&Bls[n * LSTR + kq2] = rBl0; *(short8v*)&Bls[n * LSTR + kq2 + 8] = rBl1;
    }
    __syncthreads();
    int nxt = step + 1;
    if (nxt < TOTAL) {
      int tt = nxt >> 3, kk = (nxt & 7) * 32;
      LOAD_REGS(tt, kk);
    }
    short8v ah[2], al[2], bh[4], bl[4];
#pragma unroll
    for (int i = 0; i < 2; ++i) {
      int r = wr + i * 16 + lm;
      ah[i] = *(const short8v*)&Ahs[r * LSTR + lq * 8];
      al[i] = *(const short8v*)&Als[r * LSTR + lq * 8];
    }
#pragma unroll
    for (int j = 0; j < NJ; ++j) {
      int r = wc + j * 16 + lm;
      bh[j] = *(const short8v*)&Bhs[r * LSTR + lq * 8];
      bl[j] = *(const short8v*)&Bls[r * LSTR + lq * 8];
    }
#pragma unroll
    for (int i = 0; i < 2; ++i)
#pragma unroll
      for (int j = 0; j < NJ; ++j) {
        acc[i][j] = __builtin_amdgcn_mfma_f32_16x16x32_bf16(ah[i], bh[j], acc[i][j], 0, 0, 0);
        acc[i][j] = __builtin_amdgcn_mfma_f32_16x16x32_bf16(ah[i], bl[j], acc[i][j], 0, 0, 0);
        acc[i][j] = __builtin_amdgcn_mfma_f32_16x16x32_bf16(al[i], bh[j], acc[i][j], 0, 0, 0);
      }
  }

  // ---- epilogues (frag: col=lm, row=lq*4+r) ----
  if (MODE == 2 || MODE == 3 || MODE == 5) {
#pragma unroll
    for (int i = 0; i < 2; ++i) {
#pragma unroll
      for (int r = 0; r < 4; ++r) {
        int grow = g * 256 + bym * 64 + wr + i * 16 + lq * 4 + r;
        float di = 0.f, ni = 0.f;
        if (MODE == 5) { di = dinv[grow]; ni = nrm[grow]; }
#pragma unroll
        for (int j = 0; j < NJ; ++j) {
          int gcol = col0 + wc + j * 16 + lm;
          size_t ci = (size_t)grow * 256 + gcol;
          float v = acc[i][j][r];
          if (MODE == 2) {
            Cf[ci] = v;                      // RAW dot; scale deferred to MODE 5 (D-l0)
          } else if (MODE == 3) {
            Cf[ci] = 0.5f * Cf[ci] + 0.5f * (1.f / (1.f + expf(-v)));
          } else {
            int gj = g * 256 + gcol;
            float scale = di * dinv[gj] / (ni * nrm[gj] + ZEROF);
            Cf[ci] = 0.5f * Cf[ci] * scale + 0.5f * (1.f / (1.f + expf(-v)));
          }
        }
      }
    }
  } else {
    float bsum[8];
    if (MODE == 1) {
#pragma unroll
      for (int i = 0; i < 2; ++i)
#pragma unroll
        for (int r = 0; r < 4; ++r) {
          int d = bym * 64 + wr + i * 16 + lq * 4 + r;
          bsum[i * 4 + r] = bias[d] + bias[256 + d] + bias[512 + d];
        }
    }
    u16 hv[32], lv[32];
#pragma unroll
    for (int i = 0; i < 2; ++i)
#pragma unroll
      for (int j = 0; j < NJ; ++j)
#pragma unroll
        for (int r = 0; r < 4; ++r) {
          float v = acc[i][j][r];
          if (MODE == 1) v = fmaxf(v + bsum[i * 4 + r], 0.f);
          split2(v, hv[(i * 4 + r) * NJ + j], lv[(i * 4 + r) * NJ + j]);
        }
    int ebase1 = (MODE == 1) ? (g * 256 + col0) : col0;
    int ebase2 = bym * 64;
    size_t estride = (MODE == 0) ? 8192 : 256;
#pragma unroll
    for (int ph = 0; ph < 2; ++ph) {
      __syncthreads();
      const u16* sv = ph ? lv : hv;
#pragma unroll
      for (int i = 0; i < 2; ++i)
#pragma unroll
        for (int j = 0; j < NJ; ++j)
#pragma unroll
          for (int r = 0; r < 4; ++r)
            Tt[(wc + j * 16 + lm) * TSTR + wr + i * 16 + lq * 4 + r] = sv[(i * 4 + r) * NJ + j];
      __syncthreads();
      u16* dst = ph ? Cl : Ch;
      int cc0 = tid >> 3, mm0 = (tid & 7) * 8;
#pragma unroll
      for (int it = 0; it < (HALF ? 2 : 4); ++it) {
        int cc = it * 32 + cc0;
        short8v v = *(const short8v*)&Tt[cc * TSTR + mm0];
        *(short8v*)&dst[(size_t)(ebase1 + cc) * estride + ebase2 + mm0] = v;
      }
    }
  }
}

// ---- M-build block body: dense 32x256 fp32 tile from buckets -> bf16 h/l ----
__device__ __forceinline__ void mbuild_body(
    float* tile, int bid, int l,
    const u16* __restrict__ sct, const uint2* __restrict__ recs, int nBkt,
    const float* __restrict__ Abuf, u16* __restrict__ Mbh, u16* __restrict__ Mbl) {
  const int tid = threadIdx.x;
  int gt = bid >> 3, chunk = bid & 7;
  int g = gt / 3;
  float4 z = make_float4(0.f, 0.f, 0.f, 0.f);
#pragma unroll
  for (int k = 0; k < 8; ++k) ((float4*)tile)[k * 256 + tid] = z;
  __syncthreads();
  for (int bb = tid; bb < nBkt; bb += 256) {
    unsigned sc = sct[(size_t)bb * 768 + bid];
    unsigned start = sc & 2047u, cnt = sc >> 11;
    const uint2* rp = &recs[(size_t)bb * 768 + start];
    for (unsigned k = 0; k < cnt; ++k) {
      uint2 r = rp[k];
      int s = r.x & 255, d5 = (r.x >> 8) & 31;
      float w = l ? Abuf[(size_t)(g * 256 + s) * 256 + chunk * 32 + d5]
                  : __uint_as_float(r.y);
      atomicAdd(&tile[d5 * 256 + s], w);
    }
  }
  __syncthreads();
  size_t base4 = ((size_t)gt << 14) + ((size_t)chunk << 11);  // ushort4 units
#pragma unroll
  for (int k = 0; k < 8; ++k) {
    float4 f = ((float4*)tile)[k * 256 + tid];
    ushort4 h, lo;
    split2(f.x, h.x, lo.x); split2(f.y, h.y, lo.y);
    split2(f.z, h.z, lo.z); split2(f.w, h.w, lo.w);
    ((ushort4*)Mbh)[base4 + k * 256 + tid] = h;
    ((ushort4*)Mbl)[base4 + k * 256 + tid] = lo;
  }
}

// ===== prep: mask cvt | edge bucketing (atomic-free) | transpose/split W | norms+x-split =====
__global__ void k_prep(const int* __restrict__ e0, const int* __restrict__ e1,
                       const int* __restrict__ e2, const unsigned char* __restrict__ m0,
                       const unsigned char* __restrict__ m1,
                       const float* __restrict__ W, const float* __restrict__ T,
                       const float* __restrict__ x,
                       const float* __restrict__ ew0, const float* __restrict__ ew1,
                       const float* __restrict__ ew2,
                       float* __restrict__ emf, float* __restrict__ pmf,
                       u16* __restrict__ Wth, u16* __restrict__ Wtl,
                       u16* __restrict__ sct, uint2* __restrict__ recs,
                       float* __restrict__ nrm, float* __restrict__ Spart,
                       u16* __restrict__ Hh, u16* __restrict__ Hl,
                       int E_, int nCvt, int nBkt) {
  __shared__ float tile[32][33];
  __shared__ float inv[64];
  __shared__ int nz[1];
  __shared__ unsigned int hcnt[768];
  __shared__ unsigned int hoff[768];
  __shared__ unsigned int ppart[256];
  __shared__ uint2 stage[768];
  const int b = blockIdx.x, tid = threadIdx.x;
  if (b < nCvt) {
    // ---- mask dtype detect + convert (2*NND values) ----
    if (tid == 0) nz[0] = 0;
    __syncthreads();
    int i4 = tid * 4;
    int c = (m0[i4 + 1] != 0) + (m0[i4 + 2] != 0) + (m0[i4 + 3] != 0);
    if (c) atomicAdd(&nz[0], c);
    __syncthreads();
    int fM = (nz[0] == 0);
    int i = b * 256 + tid;
    if (i < NND) {
      unsigned char v = fM ? m0[4 * i] : m0[i];
      emf[i] = 1.f - (float)(v != 0);
    } else {
      int j = i - NND;
      unsigned char v = fM ? m1[4 * j] : m1[j];
      pmf[j] = 1.f - (float)(v != 0);
    }
  } else if (b < nCvt + nBkt) {
    // ---- atomic-free edge bucketing: block-private segments, LDS hist+scan ----
    if (tid == 0) nz[0] = 0;
    hcnt[tid] = 0; hcnt[tid + 256] = 0; hcnt[tid + 512] = 0;
    __syncthreads();
    if (e0[2 * tid + 1] != 0) atomicAdd(&nz[0], 1);
    __syncthreads();
    int fE = (nz[0] == 0);   // int64-format edges
    int e = (b - nCvt) * 256 + tid;
    bool valid = (e < E_);
    int mybid[3]; unsigned int myrec[3]; float myw[3];
    if (valid) {
#pragma unroll
      for (int t = 0; t < 3; ++t) {
        const int* ei = (t == 0) ? e0 : ((t == 1) ? e1 : e2);
        int src = fE ? ei[2 * e] : ei[e];
        int dst = fE ? ei[2 * (E_ + e)] : ei[E_ + e];
        int g = src >> 8, s = src & 255, d = dst & 255;
        mybid[t] = ((g * 3 + t) << 3) | (d >> 5);
        myrec[t] = (unsigned)(((d & 31) << 8) | s);
        myw[t] = (t == 0 ? ew0 : (t == 1 ? ew1 : ew2))[e];
        atomicAdd(&hcnt[mybid[t]], 1u);
      }
    }
    __syncthreads();
    unsigned c0 = hcnt[3 * tid], c1 = hcnt[3 * tid + 1], c2 = hcnt[3 * tid + 2];
    unsigned tsum = c0 + c1 + c2;
    ppart[tid] = tsum;
    __syncthreads();
    for (int off = 1; off < 256; off <<= 1) {
      unsigned v = (tid >= off) ? ppart[tid - off] : 0u;
      __syncthreads();
      ppart[tid] += v;
      __syncthreads();
    }
    unsigned base = ppart[tid] - tsum;   // exclusive prefix
    hoff[3 * tid] = base;
    hoff[3 * tid + 1] = base + c0;
    hoff[3 * tid + 2] = base + c0 + c1;
    __syncthreads();
#pragma unroll
    for (int k = 0; k < 3; ++k) {
      int bin = tid + k * 256;
      unsigned cc = hcnt[bin]; if (cc > 31u) cc = 31u;
      sct[(size_t)(b - nCvt) * 768 + bin] = (u16)(hoff[bin] | (cc << 11));
    }
    __syncthreads();
    if (valid) {
#pragma unroll
      for (int t = 0; t < 3; ++t) {
        unsigned slot = atomicAdd(&hoff[mybid[t]], 1u);
        stage[slot] = make_uint2(myrec[t], __float_as_uint(myw[t]));
      }
    }
    __syncthreads();
    uint2* dstp = &recs[(size_t)(b - nCvt) * 768];
    dstp[tid] = stage[tid];
    dstp[tid + 256] = stage[tid + 256];
    dstp[tid + 512] = stage[tid + 512];
  } else if (b < nCvt + nBkt + 512) {
    int bb = b - nCvt - nBkt;
    int mat = bb >> 6, rem = bb & 63;
    int k0 = (rem >> 3) * 32, n0 = (rem & 7) * 32;
    const float* src = (mat < 6) ? (W + (size_t)mat * 65536) : (T + (size_t)(mat - 6) * 65536);
    int r = tid >> 3, c4 = (tid & 7) * 4;
    const float4 v = *(const float4*)&src[(size_t)(k0 + r) * 256 + n0 + c4];
    tile[r][c4 + 0] = v.x; tile[r][c4 + 1] = v.y; tile[r][c4 + 2] = v.z; tile[r][c4 + 3] = v.w;
    __syncthreads();
    float o[4] = {tile[c4 + 0][r], tile[c4 + 1][r], tile[c4 + 2][r], tile[c4 + 3][r]};
    u16 hh[4], ll[4];
#pragma unroll
    for (int q = 0; q < 4; ++q) split2(o[q], hh[q], ll[q]);
    size_t off = (size_t)mat * 65536 + (size_t)(n0 + r) * 256 + k0 + c4;
    *(ushort4*)&Wth[off] = *(ushort4*)hh;
    *(ushort4*)&Wtl[off] = *(ushort4*)ll;
  } else {
    int bn = b - nCvt - nBkt - 512;    // 0..127
    int n0 = bn * 64;
    int w = tid >> 6, lane = tid & 63;
    for (int it = 0; it < 16; ++it) {
      int nl = it * 4 + w;
      int node = n0 + nl;
      const float4 v = *(const float4*)&x[(size_t)node * 256 + lane * 4];
      u16 hh[4], ll[4];
      split2(v.x, hh[0], ll[0]); split2(v.y, hh[1], ll[1]);
      split2(v.z, hh[2], ll[2]); split2(v.w, hh[3], ll[3]);
      *(ushort4*)&Hh[(size_t)node * 256 + lane * 4] = *(ushort4*)hh;
      *(ushort4*)&Hl[(size_t)node * 256 + lane * 4] = *(ushort4*)ll;
      float s = wave_sum(v.x * v.x + v.y * v.y + v.z * v.z + v.w * v.w);
      if (lane == 0) { float nr = sqrtf(s); nrm[node] = nr; inv[nl] = 1.f / nr; }
    }
    __syncthreads();
    float s = 0.f;
    for (int i = 0; i < 64; ++i) s += x[(size_t)(n0 + i) * 256 + tid] * inv[i];
    Spart[bn * 256 + tid] = s;
  }
}

// ==== stage A (l0, max heterogeneous pack):
//  mode0 GEMM l0 (768) | M-build l0 (768) | mode2 RAW x.xT (512) | dinv (128) ====
// mode2 moved here from stageB-l0: it only needs xh/xl (prep outputs) now that the
// dinv/nrm scale is deferred to stageD-l0's epilogue (MODE 5).
__global__ __launch_bounds__(256, 2) void k_stageA(
    const u16* __restrict__ Hinh, const u16* __restrict__ Hinl,
    const u16* __restrict__ Wth, const u16* __restrict__ Wtl,
    u16* __restrict__ XWTh, u16* __restrict__ XWTl,
    const u16* __restrict__ sct, const uint2* __restrict__ recs, int nBkt,
    u16* __restrict__ Mbh, u16* __restrict__ Mbl,
    float* __restrict__ Abuf,
    const float* __restrict__ x, const float* __restrict__ Spart,
    const float* __restrict__ nrm, float* __restrict__ dinv) {
  __shared__ u16 lds[LDS_U16];
  const int b = blockIdx.x;
  if (b < 768) {
    mfma_body<0, false>(lds, Hinh, Hinl, Wth, Wtl,
                        nullptr, XWTh, XWTl, nullptr, nullptr, nullptr,
                        b >> 7, b & 127, 0);
  } else if (b < 1536) {
    mbuild_body((float*)lds, b - 768, 0, sct, recs, nBkt, nullptr, Mbh, Mbl);
  } else if (b < 2048) {
    int bb = b - 1536;
    int g = bb & 31, r = bb >> 5;      // r: 0..15 -> bxm 0..3, bym 0..3
    mfma_body<2, true>(lds, Hinh, Hinl, Hinh, Hinl, Abuf, nullptr, nullptr,
                       nullptr, nullptr, nullptr, r >> 2, r & 3, g);
  } else {
    float* Sl = (float*)lds;
    const int tid = threadIdx.x;
    float s = 0.f;
    for (int bb = 0; bb < 128; ++bb) s += Spart[bb * 256 + tid];
    Sl[tid] = s;
    __syncthreads();
    int base = (b - 2048) * 64;
    int w = tid >> 6, lane = tid & 63;
    const float4 sv = *(const float4*)&Sl[lane * 4];
    for (int it = 0; it < 16; ++it) {
      int node = base + it * 4 + w;
      const float4 v = *(const float4*)&x[(size_t)node * 256 + lane * 4];
      float s2 = wave_sum(v.x * sv.x + v.y * sv.y + v.z * sv.z + v.w * sv.w);
      if (lane == 0) {
        float rowsum = s2 / nrm[node];
        dinv[node] = rsqrtf(fabsf(rowsum) + ZEROF);
      }
    }
  }
}

// ==== stage A2 (l1, fused heterogeneous pack): mode0 GEMM l1 (768) | M-build l1 (768) ====
__global__ __launch_bounds__(256, 2) void k_stageA2(
    const u16* __restrict__ H2h, const u16* __restrict__ H2l,
    const u16* __restrict__ Wth, const u16* __restrict__ Wtl,
    u16* __restrict__ XWTh, u16* __restrict__ XWTl,
    const u16* __restrict__ sct, const uint2* __restrict__ recs, int nBkt,
    const float* __restrict__ Abuf,
    u16* __restrict__ Mbh, u16* __restrict__ Mbl) {
  __shared__ u16 lds[LDS_U16];
  const int b = blockIdx.x;
  if (b < 768) {
    mfma_body<0, false>(lds, H2h, H2l, Wth + (size_t)768 * 256, Wtl + (size_t)768 * 256,
                        nullptr, XWTh, XWTl, nullptr, nullptr, nullptr,
                        b >> 7, b & 127, 0);
  } else {
    mbuild_body((float*)lds, b - 768, 1, sct, recs, nBkt, Abuf, Mbh, Mbl);
  }
}

// ==== stage B: mode1 only (HALF 64x64, 512 blocks) ====
__global__ __launch_bounds__(256, 2) void k_stageB(
    const u16* __restrict__ XWTh, const u16* __restrict__ XWTl,
    const u16* __restrict__ Mbh, const u16* __restrict__ Mbl,
    u16* __restrict__ Houth, u16* __restrict__ Houtl, const float* __restrict__ bias) {
  __shared__ u16 lds[LDS_U16];
  const int b = blockIdx.x;
  int g = b & 31, r = b >> 5;          // r: 0..15 -> bxm 0..3, bym 0..3
  mfma_body<1, true>(lds, XWTh, XWTl, Mbh, Mbl,
                     nullptr, Houth, Houtl, nullptr, nullptr, bias,
                     r >> 2, r & 3, g);
}

// ============ stage C: mode4 (half, 512): tmp = H @ T ============
__global__ __launch_bounds__(256, 2) void k_stageC(
    const u16* __restrict__ Wth, const u16* __restrict__ Wtl, int l,
    const u16* __restrict__ Hh, const u16* __restrict__ Hl,
    u16* __restrict__ tmph, u16* __restrict__ tmpl) {
  __shared__ u16 lds[LDS_U16];
  const int b = blockIdx.x;
  mfma_body<4, true>(lds, Wth + (size_t)(6 + l) * 65536, Wtl + (size_t)(6 + l) * 65536,
                     Hh, Hl, nullptr, tmph, tmpl, nullptr, nullptr, nullptr,
                     b & 127, b >> 7, 0);
}

// ============ stage D: A update. scaled!=0 (l0): MODE 5 applies the deferred
// di*dj/(ni*nj+eps) scale to the raw x.xT before blending ============
__global__ __launch_bounds__(256, 2) void k_stageD(
    const u16* __restrict__ tmph, const u16* __restrict__ tmpl,
    const u16* __restrict__ Hh, const u16* __restrict__ Hl,
    float* __restrict__ Abuf,
    const float* __restrict__ nrm, const float* __restrict__ dinv, int scaled) {
  __shared__ u16 lds[LDS_U16];
  const int b = blockIdx.x;
  int g = b & 31, r = b >> 5;
  if (scaled)
    mfma_body<5, true>(lds, tmph, tmpl, Hh, Hl, Abuf, nullptr, nullptr,
                       nrm, dinv, nullptr, r >> 2, r & 3, g);
  else
    mfma_body<3, true>(lds, tmph, tmpl, Hh, Hl, Abuf, nullptr, nullptr,
                       nullptr, nullptr, nullptr, r >> 2, r & 3, g);
}

// ============ fused maps ============
__global__ void k_maps(const float* __restrict__ Abuf, const float* __restrict__ emf,
                       const float* __restrict__ pmf, float* __restrict__ out) {
  __shared__ float sme[256], smp[256], red[256];
  const int g = blockIdx.x, tid = threadIdx.x, w = tid >> 6, lane = tid & 63;
  const int j0 = g * 256 + lane * 4;
  const float4 pmv = *(const float4*)&pmf[j0];
  const float4 emv = *(const float4*)&emf[j0];
  for (int it = 0; it < 64; ++it) {
    int nl = it * 4 + w;
    const float4 a = *(const float4*)&Abuf[((size_t)g * 256 + nl) * 256 + lane * 4];
    float me = a.x * pmv.x + a.y * pmv.y + a.z * pmv.z + a.w * pmv.w;
    float mp = a.x * emv.x + a.y * emv.y + a.z * emv.z + a.w * emv.w;
#pragma unroll
    for (int off = 32; off > 0; off >>= 1) {
      me += __shfl_down(me, off, 64);
      mp += __shfl_down(mp, off, 64);
    }
    if (lane == 0) { sme[nl] = me; smp[nl] = mp; }
  }
  __syncthreads();
  for (int which = 0; which < 2; ++which) {
    float v = which ? smp[tid] : sme[tid];
    red[tid] = v; __syncthreads();
    for (int s = 128; s > 0; s >>= 1) { if (tid < s) red[tid] = fminf(red[tid], red[tid + s]); __syncthreads(); }
    float mn = red[0]; __syncthreads();
    red[tid] = v; __syncthreads();
    for (int s = 128; s > 0; s >>= 1) { if (tid < s) red[tid] = fmaxf(red[tid], red[tid + s]); __syncthreads(); }
    float mx = red[0]; __syncthreads();
    float m = (v - mn) / (mx - mn + ZEROF);
    red[tid] = m; __syncthreads();
    for (int s = 128; s > 0; s >>= 1) { if (tid < s) red[tid] += red[tid + s]; __syncthreads(); }
    float sum = red[0]; __syncthreads();
    out[which * NND + g * 256 + tid] = m / (sum + ZEROF);
  }
}

// ================= launch =================
extern "C" void kernel_launch(void* const* d_in, const int* in_sizes, int n_in,
                              void* d_out, int out_size, void* d_ws, size_t ws_size,
                              hipStream_t stream) {
  const float* x = (const float*)d_in[0];
  const unsigned char* em_raw = (const unsigned char*)d_in[7];
  const unsigned char* pm_raw = (const unsigned char*)d_in[8];
  const float* W  = (const float*)d_in[9];
  const float* bg = (const float*)d_in[10];
  const float* T  = (const float*)d_in[11];
  float* out = (float*)d_out;
  const int E_ = in_sizes[2];

  const int nCvt = (2 * NND) / 256;          // 64
  const int nBkt = (E_ + 255) / 256;         // 512 for E=131072

  float* ws = (float*)d_ws;
  size_t o = 0;
  float* Abuf = ws + o; o += (size_t)NND * 256;
  u16* Mbh_l0 = (u16*)(ws + o); o += (size_t)NGRP * 3 * 65536 / 2;
  u16* Mbl_l0 = (u16*)(ws + o); o += (size_t)NGRP * 3 * 65536 / 2;
  u16* Mbh_l1 = (u16*)(ws + o); o += (size_t)NGRP * 3 * 65536 / 2;
  u16* Mbl_l1 = (u16*)(ws + o); o += (size_t)NGRP * 3 * 65536 / 2;
  u16* Hh   = (u16*)(ws + o); o += (size_t)NND * 256 / 2;
  u16* Hl   = (u16*)(ws + o); o += (size_t)NND * 256 / 2;
  u16* H2h  = (u16*)(ws + o); o += (size_t)NND * 256 / 2;
  u16* H2l  = (u16*)(ws + o); o += (size_t)NND * 256 / 2;
  u16* tmph = (u16*)(ws + o); o += (size_t)NND * 256 / 2;
  u16* tmpl = (u16*)(ws + o); o += (size_t)NND * 256 / 2;
  u16* XWTh = (u16*)(ws + o); o += (size_t)768 * NND / 2;
  u16* XWTl = (u16*)(ws + o); o += (size_t)768 * NND / 2;
  u16* Wth  = (u16*)(ws + o); o += (size_t)8 * 65536 / 2;
  u16* Wtl  = (u16*)(ws + o); o += (size_t)8 * 65536 / 2;
  float* nrm   = ws + o; o += NND;
  float* dinv  = ws + o; o += NND;
  float* Spart = ws + o; o += 128 * 256;
  float* emf   = ws + o; o += NND;
  float* pmf   = ws + o; o += NND;
  u16* sct     = (u16*)(ws + o); o += (size_t)nBkt * 768 / 2;
  uint2* recs  = (uint2*)(ws + o); o += (size_t)nBkt * 768 * 2;

  const float* ew0 = (const float*)d_in[2];
  const float* ew1 = (const float*)d_in[4];
  const float* ew2 = (const float*)d_in[6];

  k_prep<<<nCvt + nBkt + 512 + 128, 256, 0, stream>>>(
      (const int*)d_in[1], (const int*)d_in[3], (const int*)d_in[5], em_raw, pm_raw,
      W, T, x, ew0, ew1, ew2, emf, pmf, Wth, Wtl, sct, recs,
      nrm, Spart, Hh, Hl, E_, nCvt, nBkt);

  // ---- layer 0 ----
  k_stageA<<<2176, 256, 0, stream>>>(Hh, Hl, Wth, Wtl, XWTh, XWTl,
                                     sct, recs, nBkt, Mbh_l0, Mbl_l0, Abuf,
                                     x, Spart, nrm, dinv);
  k_stageB<<<512, 256, 0, stream>>>(XWTh, XWTl, Mbh_l0, Mbl_l0, H2h, H2l, bg);
  k_stageC<<<512, 256, 0, stream>>>(Wth, Wtl, 0, H2h, H2l, tmph, tmpl);
  k_stageD<<<512, 256, 0, stream>>>(tmph, tmpl, H2h, H2l, Abuf, nrm, dinv, 1);

  // ---- layer 1 ----
  k_stageA2<<<1536, 256, 0, stream>>>(H2h, H2l, Wth, Wtl, XWTh, XWTl,
                                      sct, recs, nBkt, Abuf, Mbh_l1, Mbl_l1);
  k_stageB<<<512, 256, 0, stream>>>(XWTh, XWTl, Mbh_l1, Mbl_l1, Hh, Hl, bg + 768);
  k_stageC<<<512, 256, 0, stream>>>(Wth, Wtl, 1, Hh, Hl, tmph, tmpl);
  k_stageD<<<512, 256, 0, stream>>>(tmph, tmpl, Hh, Hl, Abuf, nullptr, nullptr, 0);

  k_maps<<<NGRP, 256, 0, stream>>>(Abuf, emf, pmf, out);
}